// Round 13
// baseline (930.141 us; speedup 1.0000x reference)
//
#include <hip/hip_runtime.h>
#include <hip/hip_cooperative_groups.h>

namespace cg = cooperative_groups;

constexpr int D_IN = 20;   // input feature dim
constexpr int HP   = 16;   // projection dim
constexpr int K    = 6;    // neighbors
constexpr int SAMP = 512;  // threshold sample size
constexpr int NC   = 8;    // candidate chunks (segmented buffers)
constexpr int CAPC = 192;  // per-(row,chunk) buffer capacity
constexpr float MARGIN = 0.02f;  // covers bf16-vs-fp32 dot error

typedef __attribute__((ext_vector_type(8))) short bf16x8;
typedef __attribute__((ext_vector_type(4))) float f32x4;

struct Params {
  const float *x, *Wp, *bp;
  const float *gw0, *gb0, *gw1, *gb1, *gw2, *gb2;
  const float *lg0, *lb0, *lg1, *lb1, *lg2, *lb2;
  const float *riw0, *rib0, *riw1, *rib1;
  const float *rhw0, *rhb0, *rhw1, *rhb1;
  const float *row0, *rob0, *row1, *rob1;
  float *hn; short *hnb;
  float *XWa, *XWb;
  float *evals; int *eidx;
  float *ownsum, *insum; int *indeg;
  float *rnorm, *dinv, *selfc;
  int *offsets, *cursor, *colA; float *coefA;
  float *h1, *h2, *tau;
  int *cnt; unsigned short *buf;
  float *out;
  int N;
};

// round-to-nearest-even f32 -> bf16 bits
__device__ __forceinline__ short f2bf(float f) {
  unsigned u = __float_as_uint(f);
  unsigned r = (u + 0x7fffu + ((u >> 16) & 1u)) >> 16;
  return (short)r;
}

// ---------------- per-lane top-6 in NAMED registers ----
struct Top6 { float v0,v1,v2,v3,v4,v5; int i0,i1,i2,i3,i4,i5; };

__device__ __forceinline__ void t6_init(Top6& t) {
  t.v0=t.v1=t.v2=t.v3=t.v4=t.v5=-1e30f;
  t.i0=t.i1=t.i2=t.i3=t.i4=t.i5=-1;
}

#define T6_SWAP(a,b,ia,ib) { float tv=a; a=b; b=tv; int ti=ia; ia=ib; ib=ti; }

__device__ __forceinline__ void t6_insert(Top6& t, float s, int c) {
  if (s > t.v5) {
    t.v5 = s; t.i5 = c;
    if (t.v5 > t.v4) { T6_SWAP(t.v4, t.v5, t.i4, t.i5); }
    if (t.v4 > t.v3) { T6_SWAP(t.v3, t.v4, t.i3, t.i4); }
    if (t.v3 > t.v2) { T6_SWAP(t.v2, t.v3, t.i2, t.i3); }
    if (t.v2 > t.v1) { T6_SWAP(t.v1, t.v2, t.i1, t.i2); }
    if (t.v1 > t.v0) { T6_SWAP(t.v0, t.v1, t.i0, t.i1); }
  }
}

__device__ __forceinline__ void t6_best(const Top6& t, float& cv, int& ci) {
  cv = t.v0; ci = t.i0;
  if (t.v1 > cv || (t.v1 == cv && (unsigned)t.i1 < (unsigned)ci)) { cv = t.v1; ci = t.i1; }
  if (t.v2 > cv || (t.v2 == cv && (unsigned)t.i2 < (unsigned)ci)) { cv = t.v2; ci = t.i2; }
  if (t.v3 > cv || (t.v3 == cv && (unsigned)t.i3 < (unsigned)ci)) { cv = t.v3; ci = t.i3; }
  if (t.v4 > cv || (t.v4 == cv && (unsigned)t.i4 < (unsigned)ci)) { cv = t.v4; ci = t.i4; }
  if (t.v5 > cv || (t.v5 == cv && (unsigned)t.i5 < (unsigned)ci)) { cv = t.v5; ci = t.i5; }
}

__device__ __forceinline__ void t6_consume(Top6& t, int mi) {
  if (t.i0 == mi) t.v0 = -1e30f;
  if (t.i1 == mi) t.v1 = -1e30f;
  if (t.i2 == mi) t.v2 = -1e30f;
  if (t.i3 == mi) t.v3 = -1e30f;
  if (t.i4 == mi) t.v4 = -1e30f;
  if (t.i5 == mi) t.v5 = -1e30f;
}

// load query row into 16 NAMED scalars (no arrays -> no scratch)
#define LOADQ16(ROW)                                                          \
  float4 qa = hn4[(size_t)(ROW)*4+0], qb = hn4[(size_t)(ROW)*4+1],            \
         qc = hn4[(size_t)(ROW)*4+2], qd = hn4[(size_t)(ROW)*4+3];            \
  float q0 = qa.x, q1 = qa.y, q2 = qa.z, q3 = qa.w,                           \
        q4 = qb.x, q5 = qb.y, q6 = qb.z, q7 = qb.w,                           \
        q8 = qc.x, q9 = qc.y, q10 = qc.z, q11 = qc.w,                         \
        q12 = qd.x, q13 = qd.y, q14 = qd.z, q15 = qd.w;

// sequential-fmaf dot, bit-identical order everywhere (thresh & final)
#define DOTQ16(S, J)                                                          \
  float4 ca = hn4[(size_t)(J)*4+0], cb = hn4[(size_t)(J)*4+1],                \
         cc = hn4[(size_t)(J)*4+2], cd = hn4[(size_t)(J)*4+3];                \
  float S = 0.f;                                                              \
  S = fmaf(q0,  ca.x, S); S = fmaf(q1,  ca.y, S);                             \
  S = fmaf(q2,  ca.z, S); S = fmaf(q3,  ca.w, S);                             \
  S = fmaf(q4,  cb.x, S); S = fmaf(q5,  cb.y, S);                             \
  S = fmaf(q6,  cb.z, S); S = fmaf(q7,  cb.w, S);                             \
  S = fmaf(q8,  cc.x, S); S = fmaf(q9,  cc.y, S);                             \
  S = fmaf(q10, cc.z, S); S = fmaf(q11, cc.w, S);                             \
  S = fmaf(q12, cd.x, S); S = fmaf(q13, cd.y, S);                             \
  S = fmaf(q14, cd.z, S); S = fmaf(q15, cd.w, S);

union SmU {
  int cntl[16];
  int sums[256];
  float hid32[4][2][32];
  float hid128[4][128];
};

// GCN+LN+ReLU+MLP for DOUT=32 layers, 2 rows/wave, + next-layer XW epilogue
template<int DIN, int NEXTD>
__device__ __forceinline__ void gpost32_dev(
    const Params& p, const float* __restrict__ XWsrc, const float* __restrict__ hprev,
    const float* __restrict__ gb, const float* __restrict__ lg, const float* __restrict__ lb,
    const float* __restrict__ w0, const float* __restrict__ b0,
    const float* __restrict__ w1, const float* __restrict__ b1,
    const float* __restrict__ Wnext, float* __restrict__ XWnext, float* __restrict__ outp,
    float (*hid)[2][32], int wid, int nwaves, int tid) {
  int lane = tid & 63;
  int wslot = tid >> 6;
  int sub = lane >> 5;
  int ol = lane & 31;
  int ntask = p.N >> 1;
  for (int wt = wid; wt < ntask; wt += nwaves) {
    int row = wt*2 + sub;
    float sc = p.selfc[row];
    float acc0 = sc * XWsrc[(size_t)row*32 + ol];
    int pe = p.offsets[row + 1];
    for (int q = p.offsets[row]; q < pe; ++q) {
      int jj = p.colA[q]; float cf = p.coefA[q];
      acc0 = fmaf(cf, XWsrc[(size_t)jj*32 + ol], acc0);
    }
    float u0 = acc0 + gb[ol];
    float s = u0;
#pragma unroll
    for (int m = 1; m < 32; m <<= 1) s += __shfl_xor(s, m);
    float mean = s * (1.f/32.f);
    float d0 = u0 - mean;
    float vs = d0*d0;
#pragma unroll
    for (int m = 1; m < 32; m <<= 1) vs += __shfl_xor(vs, m);
    float rstd = rsqrtf(vs * (1.f/32.f) + 1e-5f);
    float t0 = fmaxf(d0*rstd*lg[ol] + lb[ol], 0.f);
    // MLP residual
    float hp[DIN];
#pragma unroll
    for (int d = 0; d < DIN; ++d) hp[d] = hprev[(size_t)row*DIN + d];
    float a = b0[ol];
#pragma unroll
    for (int d = 0; d < DIN; ++d) a = fmaf(hp[d], w0[d*32 + ol], a);
    hid[wslot][sub][ol] = fmaxf(a, 0.f);
    float o = b1[ol];
#pragma unroll
    for (int h = 0; h < 32; ++h) o = fmaf(hid[wslot][sub][h], w1[h*32 + ol], o);
    float hv = t0 + o;
    outp[(size_t)row*32 + ol] = hv;
    // next-layer XW epilogue: share h row via LDS, each lane does NEXTD/32 cols
    hid[wslot][sub][ol] = hv;
#pragma unroll
    for (int k2 = 0; k2 < NEXTD/32; ++k2) {
      int oc = ol + 32*k2;
      float acc = 0.f;
#pragma unroll
      for (int d = 0; d < 32; ++d)
        acc = fmaf(hid[wslot][sub][d], Wnext[d*NEXTD + oc], acc);
      XWnext[(size_t)row*NEXTD + oc] = acc;
    }
  }
}

__global__ __launch_bounds__(256, 4) void k_mega(Params p) {
  cg::grid_group gg = cg::this_grid();
  __shared__ SmU sm;
  const int N = p.N;
  int tid = threadIdx.x;
  int gid = blockIdx.x * 256 + tid;
  int nthreads = gridDim.x * 256;
  int wid = (blockIdx.x << 2) | (tid >> 6);
  int nwaves = gridDim.x << 2;
  int lane = tid & 63;
  const float4* hn4 = (const float4*)p.hn;

  // ---- P1: projection + row-normalize + bf16 copy + XW0 + counter zeroing ----
  for (int i = gid; i < N; i += nthreads) {
    p.insum[i] = 0.f; p.indeg[i] = 0;
    float xr[D_IN];
#pragma unroll
    for (int d = 0; d < D_IN; ++d) xr[d] = p.x[i*D_IN + d];
    float hv[HP];
    float nrm2 = 0.f;
#pragma unroll
    for (int h = 0; h < HP; ++h) {
      float a = p.bp[h];
#pragma unroll
      for (int d = 0; d < D_IN; ++d) a += xr[d] * p.Wp[d*HP + h];
      hv[h] = a; nrm2 += a * a;
    }
    float inv = 1.f / fmaxf(sqrtf(nrm2), 1e-12f);
#pragma unroll
    for (int h = 0; h < HP; ++h) {
      float v = hv[h] * inv;
      p.hn[i*HP + h] = v;
      p.hnb[(size_t)i*32 + h] = f2bf(v);
    }
#pragma unroll
    for (int h = 0; h < HP; ++h) p.hnb[(size_t)i*32 + 16 + h] = 0;
#pragma unroll
    for (int oc = 0; oc < 32; ++oc) {
      float a = 0.f;
#pragma unroll
      for (int d = 0; d < D_IN; ++d) a += xr[d] * p.gw0[d*32 + oc];
      p.XWa[(size_t)i*32 + oc] = a;
    }
  }
  gg.sync();

  // ---- P2: threshold pass (exact 6th-largest over SAMP-sample), wave per row ----
  for (int row = wid; row < N; row += nwaves) {
    LOADQ16(row)
    Top6 t; t6_init(t);
#pragma unroll
    for (int k2 = 0; k2 < SAMP/64; ++k2) {
      int c = lane + 64*k2;
      if (c != row) {
        DOTQ16(s, c)
        t6_insert(t, s, c);
      }
    }
    float last = -1e30f;
    for (int sel = 0; sel < K; ++sel) {
      float cv; int ci;
      t6_best(t, cv, ci);
      float mv = cv; int mi = ci;
#pragma unroll
      for (int m = 1; m < 64; m <<= 1) {
        float ov = __shfl_xor(mv, m);
        int   oi = __shfl_xor(mi, m);
        if (ov > mv || (ov == mv && (unsigned)oi < (unsigned)mi)) { mv = ov; mi = oi; }
      }
      t6_consume(t, mi);
      last = mv;
    }
    if (lane == 0) p.tau[row] = last;
  }
  gg.sync();

  // ---- P3: MFMA threshold scan, segmented XCD-local appends ----
  {
    int ntask = (N/16) * NC;
    int wave = tid >> 6, half = lane >> 4, l16 = lane & 15;
    for (int t3 = blockIdx.x; t3 < ntask; t3 += gridDim.x) {
      int rb = t3 / NC, jc = t3 % NC;
      __syncthreads();
      if (tid < 16) sm.cntl[tid] = 0;
      __syncthreads();
      int r0 = rb * 16;
      bf16x8 a = *(const bf16x8*)(p.hnb + (size_t)(r0 + l16)*32 + half*8);
      float4 t4 = *(const float4*)(p.tau + r0 + half*4);
      float tm0 = t4.x - MARGIN, tm1 = t4.y - MARGIN,
            tm2 = t4.z - MARGIN, tm3 = t4.w - MARGIN;
      f32x4 zero = {0.f, 0.f, 0.f, 0.f};
      const int SPANW = N / NC / 4;     // 256
      int jb0 = jc * (N / NC) + wave * SPANW;

#define APPB(R, COND)                                                         \
      {                                                                       \
        unsigned long long mr = __ballot(COND);                               \
        if (l16 == 0) {                                                       \
          unsigned mask = (unsigned)(mr >> (16*half)) & 0xFFFFu;              \
          if (mask) {                                                         \
            int rowW = r0 + half*4 + (R);                                     \
            int pos = atomicAdd(&sm.cntl[4*half + (R)], __popc(mask));        \
            unsigned mm = mask;                                               \
            while (mm) {                                                      \
              int bx = __ffs(mm) - 1; mm &= mm - 1;                           \
              if (pos < CAPC)                                                 \
                p.buf[((size_t)rowW*NC + jc)*CAPC + pos] = (unsigned short)(jb + bx); \
              ++pos;                                                          \
            }                                                                 \
          }                                                                   \
        }                                                                     \
      }

#pragma unroll 4
      for (int jt = 0; jt < SPANW; jt += 16) {
        int jb = jb0 + jt;
        bf16x8 b = *(const bf16x8*)(p.hnb + (size_t)(jb + l16)*32 + half*8);
        f32x4 d = __builtin_amdgcn_mfma_f32_16x16x32_bf16(a, b, zero, 0, 0, 0);
        bool h0 = d[0] >= tm0, h1 = d[1] >= tm1, h2 = d[2] >= tm2, h3 = d[3] >= tm3;
        if (__any(h0 | h1 | h2 | h3)) {
          APPB(0, h0) APPB(1, h1) APPB(2, h2) APPB(3, h3)
        }
      }
#undef APPB
      __syncthreads();
      if (tid < 16)
        p.cnt[(size_t)(r0 + tid)*NC + jc] = min(sm.cntl[tid], CAPC);
    }
  }
  gg.sync();

  // ---- P4: exact fp32 top-6 from segmented candidates, wave per row ----
  for (int row = wid; row < N; row += nwaves) {
    LOADQ16(row)
    Top6 t; t6_init(t);
#pragma unroll
    for (int jc = 0; jc < NC; ++jc) {
      int nseg = p.cnt[(size_t)row*NC + jc];
      const unsigned short* seg = p.buf + ((size_t)row*NC + jc)*CAPC;
      for (int e = lane; e < nseg; e += 64) {
        int j = seg[e];
        if (j != row) {
          DOTQ16(s, j)
          t6_insert(t, s, j);
        }
      }
    }
    float osum = 0.f;
    for (int sel = 0; sel < K; ++sel) {
      float cv; int ci;
      t6_best(t, cv, ci);
      float mv = cv; int mi = ci;
#pragma unroll
      for (int m = 1; m < 64; m <<= 1) {
        float ov = __shfl_xor(mv, m);
        int   oi = __shfl_xor(mi, m);
        if (ov > mv || (ov == mv && (unsigned)oi < (unsigned)mi)) { mv = ov; mi = oi; }
      }
      t6_consume(t, mi);
      if (lane == 0) {
        p.evals[row*K + sel] = mv;
        p.eidx [row*K + sel] = mi;
        osum += mv;
        atomicAdd(&p.insum[mi], mv);
        atomicAdd(&p.indeg[mi], 1);
      }
    }
    if (lane == 0) p.ownsum[row] = osum;
  }
  gg.sync();

  // ---- P5: degree scalars (all blocks) + CSR offsets prefix scan (block 0) ----
  for (int i = gid; i < N; i += nthreads) {
    float rs = 0.5f * (p.ownsum[i] + p.insum[i]);
    float rn = 1.f / (rs + 1e-8f);
    float ds = 1.f + rs * rn;
    float di = rsqrtf(fmaxf(ds, 1e-12f));
    p.rnorm[i] = rn; p.dinv[i] = di; p.selfc[i] = di * di; p.cursor[i] = 0;
  }
  if (blockIdx.x == 0) {
    int base = tid * 32;          // assumes N == 8192
    int loc[32];
    int s = 0;
#pragma unroll
    for (int k2 = 0; k2 < 32; ++k2) { loc[k2] = s; s += K + p.indeg[base + k2]; }
    sm.sums[tid] = s;
    __syncthreads();
    for (int d = 1; d < 256; d <<= 1) {
      int v = (tid >= d) ? sm.sums[tid - d] : 0;
      __syncthreads();
      sm.sums[tid] += v;
      __syncthreads();
    }
    int excl = (tid == 0) ? 0 : sm.sums[tid - 1];
#pragma unroll
    for (int k2 = 0; k2 < 32; ++k2) p.offsets[base + k2] = excl + loc[k2];
    if (tid == 255) p.offsets[N] = sm.sums[255];
  }
  gg.sync();

  // ---- P6: fill symmetrized CSR with fused coefficients ----
  for (int e = gid; e < N * K; e += nthreads) {
    int i = e / K;
    int j = p.eidx[e];
    float v = p.evals[e];
    float base = 0.5f * v * p.dinv[i] * p.dinv[j];
    int q = atomicAdd(&p.cursor[i], 1);
    p.colA [p.offsets[i] + q] = j;
    p.coefA[p.offsets[i] + q] = base * p.rnorm[i];
    int r = atomicAdd(&p.cursor[j], 1);
    p.colA [p.offsets[j] + r] = i;
    p.coefA[p.offsets[j] + r] = base * p.rnorm[j];
  }
  gg.sync();

  // ---- P7: layer 0 (XWa stride 32) -> h1, epilogue computes XWb = h1 @ gw1 ----
  gpost32_dev<20, 32>(p, p.XWa, p.x, p.gb0, p.lg0, p.lb0,
                      p.riw0, p.rib0, p.riw1, p.rib1,
                      p.gw1, p.XWb, p.h1, sm.hid32, wid, nwaves, tid);
  gg.sync();

  // ---- P8: layer 1 (XWb stride 32) -> h2, epilogue computes XWa = h2 @ gw2 (128) ----
  gpost32_dev<32, 128>(p, p.XWb, p.h1, p.gb1, p.lg1, p.lb1,
                       p.rhw0, p.rhb0, p.rhw1, p.rhb1,
                       p.gw2, p.XWa, p.h2, sm.hid32, wid, nwaves, tid);
  gg.sync();

  // ---- P9: layer 2 (XWa stride 128) -> out, DOUT=128, HID=128, wave per row ----
  {
    int wslot = tid >> 6;
    for (int row = wid; row < N; row += nwaves) {
      float sc = p.selfc[row];
      int o0 = lane, o1 = lane + 64;
      float acc0 = sc * p.XWa[(size_t)row*128 + o0];
      float acc1 = sc * p.XWa[(size_t)row*128 + o1];
      int pe = p.offsets[row + 1];
      for (int q = p.offsets[row]; q < pe; ++q) {
        int jj = p.colA[q]; float cf = p.coefA[q];
        acc0 = fmaf(cf, p.XWa[(size_t)jj*128 + o0], acc0);
        acc1 = fmaf(cf, p.XWa[(size_t)jj*128 + o1], acc1);
      }
      float u0 = acc0 + p.gb2[o0];
      float u1 = acc1 + p.gb2[o1];
      float s = u0 + u1;
#pragma unroll
      for (int m = 1; m < 64; m <<= 1) s += __shfl_xor(s, m);
      float mean = s * (1.f/128.f);
      float d0 = u0 - mean, d1 = u1 - mean;
      float vs = d0*d0 + d1*d1;
#pragma unroll
      for (int m = 1; m < 64; m <<= 1) vs += __shfl_xor(vs, m);
      float rstd = rsqrtf(vs * (1.f/128.f) + 1e-5f);
      float t0 = fmaxf(d0*rstd*p.lg2[o0] + p.lb2[o0], 0.f);
      float t1 = fmaxf(d1*rstd*p.lg2[o1] + p.lb2[o1], 0.f);
      float hp[32];
#pragma unroll
      for (int d = 0; d < 32; ++d) hp[d] = p.h2[(size_t)row*32 + d];
      {
        float a = p.rob0[o0];
#pragma unroll
        for (int d = 0; d < 32; ++d) a = fmaf(hp[d], p.row0[d*128 + o0], a);
        sm.hid128[wslot][o0] = fmaxf(a, 0.f);
        float a1 = p.rob0[o1];
#pragma unroll
        for (int d = 0; d < 32; ++d) a1 = fmaf(hp[d], p.row0[d*128 + o1], a1);
        sm.hid128[wslot][o1] = fmaxf(a1, 0.f);
      }
      {
        float a = p.rob1[o0];
        for (int h = 0; h < 128; ++h) a = fmaf(sm.hid128[wslot][h], p.row1[h*128 + o0], a);
        p.out[(size_t)row*128 + o0] = t0 + a;
        float a1 = p.rob1[o1];
        for (int h = 0; h < 128; ++h) a1 = fmaf(sm.hid128[wslot][h], p.row1[h*128 + o1], a1);
        p.out[(size_t)row*128 + o1] = t1 + a1;
      }
    }
  }
}

extern "C" void kernel_launch(void* const* d_in, const int* in_sizes, int n_in,
                              void* d_out, int out_size, void* d_ws, size_t ws_size,
                              hipStream_t stream) {
  int N = in_sizes[0] / D_IN;   // 8192
  char* ws = (char*)d_ws;
  size_t off = 0;
  auto alloc = [&](size_t bytes) -> void* {
    void* p = ws + off;
    off += (bytes + 255) & ~(size_t)255;
    return p;
  };

  Params p;
  p.x    = (const float*)d_in[0];
  p.Wp   = (const float*)d_in[1];
  p.bp   = (const float*)d_in[2];
  p.gw0  = (const float*)d_in[3];
  p.gb0  = (const float*)d_in[4];
  p.gw1  = (const float*)d_in[5];
  p.gb1  = (const float*)d_in[6];
  p.gw2  = (const float*)d_in[7];
  p.gb2  = (const float*)d_in[8];
  p.lg0  = (const float*)d_in[9];
  p.lb0  = (const float*)d_in[10];
  p.lg1  = (const float*)d_in[11];
  p.lb1  = (const float*)d_in[12];
  p.lg2  = (const float*)d_in[13];
  p.lb2  = (const float*)d_in[14];
  p.riw0 = (const float*)d_in[15];
  p.rib0 = (const float*)d_in[16];
  p.riw1 = (const float*)d_in[17];
  p.rib1 = (const float*)d_in[18];
  p.rhw0 = (const float*)d_in[19];
  p.rhb0 = (const float*)d_in[20];
  p.rhw1 = (const float*)d_in[21];
  p.rhb1 = (const float*)d_in[22];
  p.row0 = (const float*)d_in[23];
  p.rob0 = (const float*)d_in[24];
  p.row1 = (const float*)d_in[25];
  p.rob1 = (const float*)d_in[26];
  p.out  = (float*)d_out;
  p.N = N;

  p.hn      = (float*)alloc((size_t)N * HP * 4);
  p.hnb     = (short*)alloc((size_t)N * 32 * 2);
  p.XWa     = (float*)alloc((size_t)N * 128 * 4);
  p.XWb     = (float*)alloc((size_t)N * 32 * 4);
  p.evals   = (float*)alloc((size_t)N * K * 4);
  p.eidx    = (int*)  alloc((size_t)N * K * 4);
  p.ownsum  = (float*)alloc((size_t)N * 4);
  p.insum   = (float*)alloc((size_t)N * 4);
  p.indeg   = (int*)  alloc((size_t)N * 4);
  p.rnorm   = (float*)alloc((size_t)N * 4);
  p.dinv    = (float*)alloc((size_t)N * 4);
  p.selfc   = (float*)alloc((size_t)N * 4);
  p.offsets = (int*)  alloc((size_t)(N + 1) * 4);
  p.cursor  = (int*)  alloc((size_t)N * 4);
  p.colA    = (int*)  alloc((size_t)N * K * 2 * 4);
  p.coefA   = (float*)alloc((size_t)N * K * 2 * 4);
  p.h1      = (float*)alloc((size_t)N * 32 * 4);
  p.h2      = (float*)alloc((size_t)N * 32 * 4);
  p.tau     = (float*)alloc((size_t)N * 4);
  p.cnt     = (int*)  alloc((size_t)N * NC * 4);
  p.buf     = (unsigned short*)alloc((size_t)N * NC * CAPC * 2);
  (void)ws_size; (void)n_in; (void)out_size;

  int maxB = 0;
  hipOccupancyMaxActiveBlocksPerMultiprocessor(&maxB, k_mega, 256, 0);
  if (maxB < 1) maxB = 1;
  long long cap = (long long)maxB * 256;   // 256 CUs on MI355X
  int grid = (int)(cap < 1024 ? cap : 1024);

  void* args[] = { (void*)&p };
  hipLaunchCooperativeKernel((const void*)k_mega, dim3(grid), dim3(256), args, 0, stream);
}

// Round 14
// 335.153 us; speedup vs baseline: 2.7753x; 2.7753x over previous
//
#include <hip/hip_runtime.h>

constexpr int D_IN = 20;   // input feature dim
constexpr int HP   = 16;   // projection dim
constexpr int K    = 6;    // neighbors
constexpr int SAMP = 512;  // threshold sample size
constexpr int NC   = 8;    // candidate chunks (segmented buffers)
constexpr int CAPC = 192;  // per-(row,chunk) buffer capacity
constexpr float MARGIN = 0.02f;  // covers bf16-vs-fp32 dot error

typedef __attribute__((ext_vector_type(8))) short bf16x8;
typedef __attribute__((ext_vector_type(4))) float f32x4;

// Sequential fmaf dot — MUST be bit-identical across thresh/final.
__device__ __forceinline__ float dot16_seq(const float4* q, const float4* c) {
  float s = 0.f;
#pragma unroll
  for (int m = 0; m < 4; ++m) {
    s = fmaf(q[m].x, c[m].x, s);
    s = fmaf(q[m].y, c[m].y, s);
    s = fmaf(q[m].z, c[m].z, s);
    s = fmaf(q[m].w, c[m].w, s);
  }
  return s;
}

// round-to-nearest-even f32 -> bf16 bits
__device__ __forceinline__ short f2bf(float f) {
  unsigned u = __float_as_uint(f);
  unsigned r = (u + 0x7fffu + ((u >> 16) & 1u)) >> 16;
  return (short)r;
}

// ---- projection + row-normalize + bf16 copy + XW0 + counter zeroing ----
__global__ void k_proj(const float* __restrict__ x, const float* __restrict__ Wp,
                       const float* __restrict__ bp, const float* __restrict__ gw0,
                       float* __restrict__ hn, short* __restrict__ hnb,
                       float* __restrict__ XW0,
                       float* __restrict__ insum, int* __restrict__ indeg, int N) {
  int i = blockIdx.x * blockDim.x + threadIdx.x;
  if (i >= N) return;
  insum[i] = 0.f; indeg[i] = 0;
  float xr[D_IN];
#pragma unroll
  for (int d = 0; d < D_IN; ++d) xr[d] = x[i*D_IN + d];
  float hv[HP];
  float nrm2 = 0.f;
#pragma unroll
  for (int h = 0; h < HP; ++h) {
    float a = bp[h];
#pragma unroll
    for (int d = 0; d < D_IN; ++d) a += xr[d] * Wp[d*HP + h];
    hv[h] = a;
    nrm2 += a * a;
  }
  float inv = 1.f / fmaxf(sqrtf(nrm2), 1e-12f);
#pragma unroll
  for (int h = 0; h < HP; ++h) {
    float v = hv[h] * inv;
    hn[i*HP + h] = v;
    hnb[(size_t)i*32 + h] = f2bf(v);
  }
#pragma unroll
  for (int h = 0; h < HP; ++h) hnb[(size_t)i*32 + 16 + h] = 0;
  // fused XW0 = x @ gw0 (bias added in gpost)
#pragma unroll
  for (int oc = 0; oc < 32; ++oc) {
    float a = 0.f;
#pragma unroll
    for (int d = 0; d < D_IN; ++d) a += xr[d] * gw0[d*32 + oc];
    XW0[(size_t)i*32 + oc] = a;
  }
}

// ---------------- per-lane top-6 in NAMED registers ----
struct Top6 { float v0,v1,v2,v3,v4,v5; int i0,i1,i2,i3,i4,i5; };

__device__ __forceinline__ void t6_init(Top6& t) {
  t.v0=t.v1=t.v2=t.v3=t.v4=t.v5=-1e30f;
  t.i0=t.i1=t.i2=t.i3=t.i4=t.i5=-1;
}

#define T6_SWAP(a,b,ia,ib) { float tv=a; a=b; b=tv; int ti=ia; ia=ib; ib=ti; }

__device__ __forceinline__ void t6_insert(Top6& t, float s, int c) {
  if (s > t.v5) {
    t.v5 = s; t.i5 = c;
    if (t.v5 > t.v4) { T6_SWAP(t.v4, t.v5, t.i4, t.i5); }
    if (t.v4 > t.v3) { T6_SWAP(t.v3, t.v4, t.i3, t.i4); }
    if (t.v3 > t.v2) { T6_SWAP(t.v2, t.v3, t.i2, t.i3); }
    if (t.v2 > t.v1) { T6_SWAP(t.v1, t.v2, t.i1, t.i2); }
    if (t.v1 > t.v0) { T6_SWAP(t.v0, t.v1, t.i0, t.i1); }
  }
}

__device__ __forceinline__ void t6_best(const Top6& t, float& cv, int& ci) {
  cv = t.v0; ci = t.i0;
  if (t.v1 > cv || (t.v1 == cv && (unsigned)t.i1 < (unsigned)ci)) { cv = t.v1; ci = t.i1; }
  if (t.v2 > cv || (t.v2 == cv && (unsigned)t.i2 < (unsigned)ci)) { cv = t.v2; ci = t.i2; }
  if (t.v3 > cv || (t.v3 == cv && (unsigned)t.i3 < (unsigned)ci)) { cv = t.v3; ci = t.i3; }
  if (t.v4 > cv || (t.v4 == cv && (unsigned)t.i4 < (unsigned)ci)) { cv = t.v4; ci = t.i4; }
  if (t.v5 > cv || (t.v5 == cv && (unsigned)t.i5 < (unsigned)ci)) { cv = t.v5; ci = t.i5; }
}

__device__ __forceinline__ void t6_consume(Top6& t, int mi) {
  if (t.i0 == mi) t.v0 = -1e30f;
  if (t.i1 == mi) t.v1 = -1e30f;
  if (t.i2 == mi) t.v2 = -1e30f;
  if (t.i3 == mi) t.v3 = -1e30f;
  if (t.i4 == mi) t.v4 = -1e30f;
  if (t.i5 == mi) t.v5 = -1e30f;
}

// ------- fused: per-block threshold recompute + MFMA scan, segmented appends -----
// Grid (N/16) x NC. Each block: (1) computes tau (exact 6th-largest over the
// SAMP-sample) for its 16 rows — identical fp32 math in every chunk block ->
// deterministic; (2) MFMA-scans its candidate chunk, appending hits to its
// private (row,chunk) buffer segment. LDS counters only; no global atomics.
__global__ __launch_bounds__(256) void k_scan2(
    const float* __restrict__ hn, const short* __restrict__ hnb,
    int* __restrict__ cnt, unsigned short* __restrict__ buf, int N) {
  __shared__ float tau_s[16];
  __shared__ int cntl[16];
  int rb = blockIdx.x / NC;
  int jc = blockIdx.x % NC;
  int wave = threadIdx.x >> 6, lane = threadIdx.x & 63;
  int r0 = rb * 16;
  const float4* hn4 = (const float4*)hn;

  // ---- thresh: wave w computes rows r0+4w .. r0+4w+3 ----
  for (int r = 0; r < 4; ++r) {
    int row = r0 + wave*4 + r;
    float4 q[4];
#pragma unroll
    for (int m = 0; m < 4; ++m) q[m] = hn4[(size_t)row*4 + m];
    Top6 t; t6_init(t);
#pragma unroll
    for (int k2 = 0; k2 < SAMP/64; ++k2) {
      int c = lane + 64*k2;
      if (c != row) {
        float4 cv[4];
#pragma unroll
        for (int m = 0; m < 4; ++m) cv[m] = hn4[(size_t)c*4 + m];
        float s = dot16_seq(q, cv);
        t6_insert(t, s, c);
      }
    }
    float last = -1e30f;
    for (int sel = 0; sel < K; ++sel) {
      float cv; int ci;
      t6_best(t, cv, ci);
      float mv = cv; int mi = ci;
#pragma unroll
      for (int m = 1; m < 64; m <<= 1) {
        float ov = __shfl_xor(mv, m);
        int   oi = __shfl_xor(mi, m);
        if (ov > mv || (ov == mv && (unsigned)oi < (unsigned)mi)) { mv = ov; mi = oi; }
      }
      t6_consume(t, mi);
      last = mv;
    }
    if (lane == 0) tau_s[wave*4 + r] = last;
  }
  __syncthreads();

  int half = lane >> 4;              // 0..3
  int l16  = lane & 15;
  if (threadIdx.x < 16) cntl[threadIdx.x] = 0;
  float tm0 = tau_s[half*4+0] - MARGIN, tm1 = tau_s[half*4+1] - MARGIN,
        tm2 = tau_s[half*4+2] - MARGIN, tm3 = tau_s[half*4+3] - MARGIN;
  __syncthreads();

  bf16x8 a = *(const bf16x8*)(hnb + (size_t)(r0 + l16)*32 + half*8);
  f32x4 zero = {0.f, 0.f, 0.f, 0.f};
  const int SPANW = N / NC / 4;      // 256
  int jb0 = jc * (N / NC) + wave * SPANW;

#define APPB(R, COND)                                                        \
  {                                                                          \
    unsigned long long mr = __ballot(COND);                                  \
    if (l16 == 0) {                                                          \
      unsigned mask = (unsigned)(mr >> (16*half)) & 0xFFFFu;                 \
      if (mask) {                                                            \
        int row = r0 + half*4 + (R);                                         \
        int pos = atomicAdd(&cntl[4*half + (R)], __popc(mask));              \
        unsigned mm = mask;                                                  \
        while (mm) {                                                         \
          int bx = __ffs(mm) - 1; mm &= mm - 1;                              \
          if (pos < CAPC)                                                    \
            buf[((size_t)row*NC + jc)*CAPC + pos] = (unsigned short)(jb + bx); \
          ++pos;                                                             \
        }                                                                    \
      }                                                                      \
    }                                                                        \
  }

#pragma unroll 4
  for (int jt = 0; jt < SPANW; jt += 16) {
    int jb = jb0 + jt;
    bf16x8 b = *(const bf16x8*)(hnb + (size_t)(jb + l16)*32 + half*8);
    f32x4 d = __builtin_amdgcn_mfma_f32_16x16x32_bf16(a, b, zero, 0, 0, 0);
    bool h0 = d[0] >= tm0, h1 = d[1] >= tm1, h2 = d[2] >= tm2, h3 = d[3] >= tm3;
    if (__any(h0 | h1 | h2 | h3)) {
      APPB(0, h0) APPB(1, h1) APPB(2, h2) APPB(3, h3)
    }
  }
#undef APPB

  __syncthreads();
  if (threadIdx.x < 16)
    cnt[(size_t)(r0 + threadIdx.x)*NC + jc] = min(cntl[threadIdx.x], CAPC);
}

// ---------------- exact top-6 from segmented candidates, wave per row ----
__global__ __launch_bounds__(256) void k_final(
    const float* __restrict__ hn, const unsigned short* __restrict__ buf,
    const int* __restrict__ cnt,
    float* __restrict__ evals, int* __restrict__ eidx,
    float* __restrict__ ownsum, float* insum, int* indeg, int N) {
  int wave = threadIdx.x >> 6, lane = threadIdx.x & 63;
  int row = blockIdx.x * 4 + wave;
  const float4* hn4 = (const float4*)hn;
  float4 q[4];
#pragma unroll
  for (int m = 0; m < 4; ++m) q[m] = hn4[(size_t)row*4 + m];
  Top6 t; t6_init(t);
#pragma unroll
  for (int jc = 0; jc < NC; ++jc) {
    int nseg = cnt[(size_t)row*NC + jc];
    const unsigned short* seg = buf + ((size_t)row*NC + jc)*CAPC;
    for (int e = lane; e < nseg; e += 64) {
      int j = seg[e];
      if (j != row) {
        float4 cv[4];
#pragma unroll
        for (int m = 0; m < 4; ++m) cv[m] = hn4[(size_t)j*4 + m];
        float s = dot16_seq(q, cv);
        t6_insert(t, s, j);
      }
    }
  }
  float osum = 0.f;
  for (int sel = 0; sel < K; ++sel) {
    float cv; int ci;
    t6_best(t, cv, ci);
    float mv = cv; int mi = ci;
#pragma unroll
    for (int m = 1; m < 64; m <<= 1) {
      float ov = __shfl_xor(mv, m);
      int   oi = __shfl_xor(mi, m);
      if (ov > mv || (ov == mv && (unsigned)oi < (unsigned)mi)) { mv = ov; mi = oi; }
    }
    t6_consume(t, mi);
    if (lane == 0) {
      evals[row*K + sel] = mv;
      eidx [row*K + sel] = mi;
      osum += mv;
      atomicAdd(&insum[mi], mv);
      atomicAdd(&indeg[mi], 1);
    }
  }
  if (lane == 0) ownsum[row] = osum;
}

// ------- fused: degree scalars + exclusive scan of (K + indeg) -> CSR offsets ----
__global__ __launch_bounds__(1024) void k_scan(
    const int* __restrict__ indeg, const float* __restrict__ ownsum,
    const float* __restrict__ insum,
    float* __restrict__ rnorm, float* __restrict__ dinv, float* __restrict__ selfc,
    int* __restrict__ cursor, int* __restrict__ offsets, int N) {
  __shared__ int sums[1024];
  int tid = threadIdx.x;
  int per = N >> 10;           // assumes N multiple of 1024
  int base = tid * per;
  int loc[16];
  int s = 0;
  for (int k = 0; k < per; ++k) {
    int i = base + k;
    float rs = 0.5f * (ownsum[i] + insum[i]);
    float rn = 1.f / (rs + 1e-8f);
    float ds = 1.f + rs * rn;
    float di = rsqrtf(fmaxf(ds, 1e-12f));
    rnorm[i] = rn; dinv[i] = di; selfc[i] = di * di; cursor[i] = 0;
    loc[k] = s; s += K + indeg[i];
  }
  sums[tid] = s;
  __syncthreads();
  for (int d = 1; d < 1024; d <<= 1) {
    int v = (tid >= d) ? sums[tid - d] : 0;
    __syncthreads();
    sums[tid] += v;
    __syncthreads();
  }
  int excl = (tid == 0) ? 0 : sums[tid - 1];
  for (int k = 0; k < per; ++k) offsets[base + k] = excl + loc[k];
  if (tid == 1023) offsets[N] = sums[1023];
}

// ---------------- fill symmetrized CSR with fused coefficients ----------------
__global__ void k_fill(const float* __restrict__ evals, const int* __restrict__ eidx,
                       const float* __restrict__ rnorm, const float* __restrict__ dinv,
                       const int* __restrict__ offsets, int* cursor,
                       int* __restrict__ col, float* __restrict__ coef, int N) {
  int e = blockIdx.x * blockDim.x + threadIdx.x;
  if (e >= N * K) return;
  int i = e / K;
  int j = eidx[e];
  float v = evals[e];
  float base = 0.5f * v * dinv[i] * dinv[j];
  int p = atomicAdd(&cursor[i], 1);
  col [offsets[i] + p] = j;
  coef[offsets[i] + p] = base * rnorm[i];
  int q = atomicAdd(&cursor[j], 1);
  col [offsets[j] + q] = i;
  coef[offsets[j] + q] = base * rnorm[j];
}

// ---- DOUT=32 layer: GCN + LN + ReLU + MLP residual, 2 rows/wave,
// ---- epilogue computes next layer's XW row-locally (h shared via LDS).
template<int DIN, int NEXTD>
__global__ __launch_bounds__(256) void k_gpost32(
    const float* __restrict__ XWsrc, const int* __restrict__ offsets,
    const int* __restrict__ col, const float* __restrict__ coef,
    const float* __restrict__ selfc,
    const float* __restrict__ gb, const float* __restrict__ lg, const float* __restrict__ lb,
    const float* __restrict__ hprev,
    const float* __restrict__ w0, const float* __restrict__ b0,
    const float* __restrict__ w1, const float* __restrict__ b1,
    const float* __restrict__ Wnext, float* __restrict__ XWnext,
    float* __restrict__ outp, int N) {
  __shared__ float hid[4][2][32];
  int tid = threadIdx.x;
  int lane = tid & 63, wslot = tid >> 6;
  int sub = lane >> 5, ol = lane & 31;
  int row = (blockIdx.x * 4 + wslot) * 2 + sub;

  float sc = selfc[row];
  float acc0 = sc * XWsrc[(size_t)row*32 + ol];
  int pe = offsets[row + 1];
  for (int q = offsets[row]; q < pe; ++q) {
    int jj = col[q]; float cf = coef[q];
    acc0 = fmaf(cf, XWsrc[(size_t)jj*32 + ol], acc0);
  }
  float u0 = acc0 + gb[ol];
  float s = u0;
#pragma unroll
  for (int m = 1; m < 32; m <<= 1) s += __shfl_xor(s, m);
  float mean = s * (1.f/32.f);
  float d0 = u0 - mean;
  float vs = d0*d0;
#pragma unroll
  for (int m = 1; m < 32; m <<= 1) vs += __shfl_xor(vs, m);
  float rstd = rsqrtf(vs * (1.f/32.f) + 1e-5f);
  float t0 = fmaxf(d0*rstd*lg[ol] + lb[ol], 0.f);

  // MLP residual (hidden via per-wave LDS; same-wave lockstep -> no barrier)
  float hp[DIN];
#pragma unroll
  for (int d = 0; d < DIN; ++d) hp[d] = hprev[(size_t)row*DIN + d];
  float a = b0[ol];
#pragma unroll
  for (int d = 0; d < DIN; ++d) a = fmaf(hp[d], w0[d*32 + ol], a);
  hid[wslot][sub][ol] = fmaxf(a, 0.f);
  float o = b1[ol];
#pragma unroll
  for (int h = 0; h < 32; ++h) o = fmaf(hid[wslot][sub][h], w1[h*32 + ol], o);
  float hv = t0 + o;
  outp[(size_t)row*32 + ol] = hv;

  // epilogue: XWnext = h @ Wnext (h row shared via LDS)
  hid[wslot][sub][ol] = hv;
#pragma unroll
  for (int k2 = 0; k2 < NEXTD/32; ++k2) {
    int oc = ol + 32*k2;
    float acc = 0.f;
#pragma unroll
    for (int d = 0; d < 32; ++d)
      acc = fmaf(hid[wslot][sub][d], Wnext[d*NEXTD + oc], acc);
    XWnext[(size_t)row*NEXTD + oc] = acc;
  }
}

// ---------------- final layer (DOUT=128): gather + LN + relu + MLP residual ----
__global__ __launch_bounds__(256) void k_gpost128(
    const float* __restrict__ XW, const int* __restrict__ offsets,
    const int* __restrict__ col, const float* __restrict__ coef,
    const float* __restrict__ selfc,
    const float* __restrict__ b, const float* __restrict__ g, const float* __restrict__ bt,
    const float* __restrict__ hprev,
    const float* __restrict__ w0, const float* __restrict__ b0,
    const float* __restrict__ w1, const float* __restrict__ b1,
    float* __restrict__ out, int N) {
  __shared__ float hid_s[4][128];
  int wslot = threadIdx.x >> 6;
  int row   = (blockIdx.x * blockDim.x + threadIdx.x) >> 6;
  int lane  = threadIdx.x & 63;
  int o0 = lane, o1 = lane + 64;

  float sc = selfc[row];
  float acc0 = sc * XW[(size_t)row*128 + o0];
  float acc1 = sc * XW[(size_t)row*128 + o1];
  int pe = offsets[row + 1];
  for (int p = offsets[row]; p < pe; ++p) {
    int jj = col[p]; float cf = coef[p];
    acc0 = fmaf(cf, XW[(size_t)jj*128 + o0], acc0);
    acc1 = fmaf(cf, XW[(size_t)jj*128 + o1], acc1);
  }
  float u0 = acc0 + b[o0];
  float u1 = acc1 + b[o1];

  float s = u0 + u1;
#pragma unroll
  for (int m = 1; m < 64; m <<= 1) s += __shfl_xor(s, m);
  float mean = s * (1.f/128.f);
  float d0 = u0 - mean, d1 = u1 - mean;
  float vs = d0*d0 + d1*d1;
#pragma unroll
  for (int m = 1; m < 64; m <<= 1) vs += __shfl_xor(vs, m);
  float rstd = rsqrtf(vs * (1.f/128.f) + 1e-5f);
  float t0 = fmaxf(d0*rstd*g[o0] + bt[o0], 0.f);
  float t1 = fmaxf(d1*rstd*g[o1] + bt[o1], 0.f);

  float hp[32];
#pragma unroll
  for (int d = 0; d < 32; ++d) hp[d] = hprev[(size_t)row*32 + d];
  {
    float a = b0[o0];
#pragma unroll
    for (int d = 0; d < 32; ++d) a = fmaf(hp[d], w0[d*128 + o0], a);
    hid_s[wslot][o0] = fmaxf(a, 0.f);
    float a1 = b0[o1];
#pragma unroll
    for (int d = 0; d < 32; ++d) a1 = fmaf(hp[d], w0[d*128 + o1], a1);
    hid_s[wslot][o1] = fmaxf(a1, 0.f);
  }
  __syncthreads();
  {
    float a = b1[o0];
    for (int h = 0; h < 128; ++h) a = fmaf(hid_s[wslot][h], w1[h*128 + o0], a);
    out[(size_t)row*128 + o0] = t0 + a;
    float a1 = b1[o1];
    for (int h = 0; h < 128; ++h) a1 = fmaf(hid_s[wslot][h], w1[h*128 + o1], a1);
    out[(size_t)row*128 + o1] = t1 + a1;
  }
}

extern "C" void kernel_launch(void* const* d_in, const int* in_sizes, int n_in,
                              void* d_out, int out_size, void* d_ws, size_t ws_size,
                              hipStream_t stream) {
  const float* x    = (const float*)d_in[0];
  const float* Wp   = (const float*)d_in[1];
  const float* bp   = (const float*)d_in[2];
  const float* gw0  = (const float*)d_in[3];
  const float* gb0  = (const float*)d_in[4];
  const float* gw1  = (const float*)d_in[5];
  const float* gb1  = (const float*)d_in[6];
  const float* gw2  = (const float*)d_in[7];
  const float* gb2  = (const float*)d_in[8];
  const float* lg0  = (const float*)d_in[9];
  const float* lb0  = (const float*)d_in[10];
  const float* lg1  = (const float*)d_in[11];
  const float* lb1  = (const float*)d_in[12];
  const float* lg2  = (const float*)d_in[13];
  const float* lb2  = (const float*)d_in[14];
  const float* riw0 = (const float*)d_in[15];
  const float* rib0 = (const float*)d_in[16];
  const float* riw1 = (const float*)d_in[17];
  const float* rib1 = (const float*)d_in[18];
  const float* rhw0 = (const float*)d_in[19];
  const float* rhb0 = (const float*)d_in[20];
  const float* rhw1 = (const float*)d_in[21];
  const float* rhb1 = (const float*)d_in[22];
  const float* row0 = (const float*)d_in[23];
  const float* rob0 = (const float*)d_in[24];
  const float* row1 = (const float*)d_in[25];
  const float* rob1 = (const float*)d_in[26];
  int N = in_sizes[0] / D_IN;   // 8192
  float* out = (float*)d_out;

  char* ws = (char*)d_ws;
  size_t off = 0;
  auto alloc = [&](size_t bytes) -> void* {
    void* p = ws + off;
    off += (bytes + 255) & ~(size_t)255;
    return p;
  };
  float* hn      = (float*)alloc((size_t)N * HP * 4);
  float* evals   = (float*)alloc((size_t)N * K * 4);
  int*   eidx    = (int*)  alloc((size_t)N * K * 4);
  float* ownsum  = (float*)alloc((size_t)N * 4);
  float* insum   = (float*)alloc((size_t)N * 4);
  int*   indeg   = (int*)  alloc((size_t)N * 4);
  float* rnorm   = (float*)alloc((size_t)N * 4);
  float* dinv    = (float*)alloc((size_t)N * 4);
  float* selfc   = (float*)alloc((size_t)N * 4);
  int*   offsets = (int*)  alloc((size_t)(N + 1) * 4);
  int*   cursor  = (int*)  alloc((size_t)N * 4);
  int*   colA    = (int*)  alloc((size_t)N * K * 2 * 4);
  float* coefA   = (float*)alloc((size_t)N * K * 2 * 4);
  float* XWa     = (float*)alloc((size_t)N * 128 * 4);
  float* XWb     = (float*)alloc((size_t)N * 32 * 4);
  float* h1      = (float*)alloc((size_t)N * 32 * 4);
  float* h2      = (float*)alloc((size_t)N * 32 * 4);
  int*   cnt     = (int*)  alloc((size_t)N * NC * 4);
  unsigned short* buf = (unsigned short*)alloc((size_t)N * NC * CAPC * 2);
  short* hnb     = (short*)alloc((size_t)N * 32 * 2);
  (void)ws_size; (void)n_in; (void)out_size;

  const int B = 256;
  hipLaunchKernelGGL(k_proj, dim3((N + B - 1) / B), dim3(B), 0, stream,
                     x, Wp, bp, gw0, hn, hnb, XWa, insum, indeg, N);
  // fused thresh + MFMA scan: (N/16) row groups x NC chunks
  hipLaunchKernelGGL(k_scan2, dim3((N / 16) * NC), dim3(B), 0, stream,
                     hn, hnb, cnt, buf, N);
  hipLaunchKernelGGL(k_final, dim3(N / 4), dim3(B), 0, stream,
                     hn, buf, cnt, evals, eidx, ownsum, insum, indeg, N);
  hipLaunchKernelGGL(k_scan, dim3(1), dim3(1024), 0, stream,
                     indeg, ownsum, insum, rnorm, dinv, selfc, cursor, offsets, N);
  hipLaunchKernelGGL(k_fill, dim3((N * K + B - 1) / B), dim3(B), 0, stream,
                     evals, eidx, rnorm, dinv, offsets, cursor, colA, coefA, N);

  // layer 0: XWa(stride32) -> h1, epilogue XWb = h1 @ gw1
  hipLaunchKernelGGL((k_gpost32<20, 32>), dim3(N / 8), dim3(B), 0, stream,
                     XWa, offsets, colA, coefA, selfc, gb0, lg0, lb0,
                     x, riw0, rib0, riw1, rib1, gw1, XWb, h1, N);
  // layer 1: XWb(stride32) -> h2, epilogue XWa = h2 @ gw2 (stride128)
  hipLaunchKernelGGL((k_gpost32<32, 128>), dim3(N / 8), dim3(B), 0, stream,
                     XWb, offsets, colA, coefA, selfc, gb1, lg1, lb1,
                     h1, rhw0, rhb0, rhw1, rhb1, gw2, XWa, h2, N);
  // layer 2: XWa(stride128) -> out
  hipLaunchKernelGGL(k_gpost128, dim3(N / 4), dim3(B), 0, stream,
                     XWa, offsets, colA, coefA, selfc, gb2, lg2, lb2,
                     h2, row0, rob0, row1, rob1, out, N);
}

// Round 15
// 200.920 us; speedup vs baseline: 4.6294x; 1.6681x over previous
//
#include <hip/hip_runtime.h>

constexpr int D_IN = 20;   // input feature dim
constexpr int HP   = 16;   // projection dim
constexpr int K    = 6;    // neighbors
constexpr int SAMP = 512;  // threshold sample size
constexpr int NC   = 8;    // candidate chunks (segmented buffers)
constexpr int CAPC = 192;  // per-(row,chunk) buffer capacity
constexpr float MARGIN = 0.02f;  // covers bf16-vs-fp32 dot error

typedef __attribute__((ext_vector_type(8))) short bf16x8;
typedef __attribute__((ext_vector_type(4))) float f32x4;

// Sequential fmaf dot — MUST be bit-identical across thresh/final.
__device__ __forceinline__ float dot16_seq(const float4* q, const float4* c) {
  float s = 0.f;
#pragma unroll
  for (int m = 0; m < 4; ++m) {
    s = fmaf(q[m].x, c[m].x, s);
    s = fmaf(q[m].y, c[m].y, s);
    s = fmaf(q[m].z, c[m].z, s);
    s = fmaf(q[m].w, c[m].w, s);
  }
  return s;
}

// round-to-nearest-even f32 -> bf16 bits
__device__ __forceinline__ short f2bf(float f) {
  unsigned u = __float_as_uint(f);
  unsigned r = (u + 0x7fffu + ((u >> 16) & 1u)) >> 16;
  return (short)r;
}

// ---- projection + row-normalize + bf16 copy + XW0 + counter zeroing ----
__global__ void k_proj(const float* __restrict__ x, const float* __restrict__ Wp,
                       const float* __restrict__ bp, const float* __restrict__ gw0,
                       float* __restrict__ hn, short* __restrict__ hnb,
                       float* __restrict__ XW0,
                       float* __restrict__ insum, int* __restrict__ indeg, int N) {
  int i = blockIdx.x * blockDim.x + threadIdx.x;
  if (i >= N) return;
  insum[i] = 0.f; indeg[i] = 0;
  float xr[D_IN];
#pragma unroll
  for (int d = 0; d < D_IN; ++d) xr[d] = x[i*D_IN + d];
  float hv[HP];
  float nrm2 = 0.f;
#pragma unroll
  for (int h = 0; h < HP; ++h) {
    float a = bp[h];
#pragma unroll
    for (int d = 0; d < D_IN; ++d) a += xr[d] * Wp[d*HP + h];
    hv[h] = a;
    nrm2 += a * a;
  }
  float inv = 1.f / fmaxf(sqrtf(nrm2), 1e-12f);
#pragma unroll
  for (int h = 0; h < HP; ++h) {
    float v = hv[h] * inv;
    hn[i*HP + h] = v;
    hnb[(size_t)i*32 + h] = f2bf(v);
  }
#pragma unroll
  for (int h = 0; h < HP; ++h) hnb[(size_t)i*32 + 16 + h] = 0;
  // fused XW0 = x @ gw0 (bias added in gpost)
#pragma unroll
  for (int oc = 0; oc < 32; ++oc) {
    float a = 0.f;
#pragma unroll
    for (int d = 0; d < D_IN; ++d) a += xr[d] * gw0[d*32 + oc];
    XW0[(size_t)i*32 + oc] = a;
  }
}

// ---------------- per-lane top-6 in NAMED registers ----
struct Top6 { float v0,v1,v2,v3,v4,v5; int i0,i1,i2,i3,i4,i5; };

__device__ __forceinline__ void t6_init(Top6& t) {
  t.v0=t.v1=t.v2=t.v3=t.v4=t.v5=-1e30f;
  t.i0=t.i1=t.i2=t.i3=t.i4=t.i5=-1;
}

#define T6_SWAP(a,b,ia,ib) { float tv=a; a=b; b=tv; int ti=ia; ia=ib; ib=ti; }

__device__ __forceinline__ void t6_insert(Top6& t, float s, int c) {
  if (s > t.v5) {
    t.v5 = s; t.i5 = c;
    if (t.v5 > t.v4) { T6_SWAP(t.v4, t.v5, t.i4, t.i5); }
    if (t.v4 > t.v3) { T6_SWAP(t.v3, t.v4, t.i3, t.i4); }
    if (t.v3 > t.v2) { T6_SWAP(t.v2, t.v3, t.i2, t.i3); }
    if (t.v2 > t.v1) { T6_SWAP(t.v1, t.v2, t.i1, t.i2); }
    if (t.v1 > t.v0) { T6_SWAP(t.v0, t.v1, t.i0, t.i1); }
  }
}

__device__ __forceinline__ void t6_best(const Top6& t, float& cv, int& ci) {
  cv = t.v0; ci = t.i0;
  if (t.v1 > cv || (t.v1 == cv && (unsigned)t.i1 < (unsigned)ci)) { cv = t.v1; ci = t.i1; }
  if (t.v2 > cv || (t.v2 == cv && (unsigned)t.i2 < (unsigned)ci)) { cv = t.v2; ci = t.i2; }
  if (t.v3 > cv || (t.v3 == cv && (unsigned)t.i3 < (unsigned)ci)) { cv = t.v3; ci = t.i3; }
  if (t.v4 > cv || (t.v4 == cv && (unsigned)t.i4 < (unsigned)ci)) { cv = t.v4; ci = t.i4; }
  if (t.v5 > cv || (t.v5 == cv && (unsigned)t.i5 < (unsigned)ci)) { cv = t.v5; ci = t.i5; }
}

__device__ __forceinline__ void t6_consume(Top6& t, int mi) {
  if (t.i0 == mi) t.v0 = -1e30f;
  if (t.i1 == mi) t.v1 = -1e30f;
  if (t.i2 == mi) t.v2 = -1e30f;
  if (t.i3 == mi) t.v3 = -1e30f;
  if (t.i4 == mi) t.v4 = -1e30f;
  if (t.i5 == mi) t.v5 = -1e30f;
}

// ---------------- threshold pass: exact 6th-largest over SAMP-sample, wave per row
__global__ __launch_bounds__(256) void k_thresh(const float* __restrict__ hn,
                                                float* __restrict__ tau, int N) {
  int wave = threadIdx.x >> 6, lane = threadIdx.x & 63;
  int row = blockIdx.x * 4 + wave;
  const float4* hn4 = (const float4*)hn;
  float4 q[4];
#pragma unroll
  for (int m = 0; m < 4; ++m) q[m] = hn4[(size_t)row*4 + m];
  Top6 t; t6_init(t);
#pragma unroll
  for (int k = 0; k < SAMP/64; ++k) {
    int c = lane + 64*k;
    if (c != row) {
      float4 cv[4];
#pragma unroll
      for (int m = 0; m < 4; ++m) cv[m] = hn4[(size_t)c*4 + m];
      float s = dot16_seq(q, cv);
      t6_insert(t, s, c);
    }
  }
  float last = -1e30f;
  for (int sel = 0; sel < K; ++sel) {
    float cv; int ci;
    t6_best(t, cv, ci);
    float mv = cv; int mi = ci;
#pragma unroll
    for (int m = 1; m < 64; m <<= 1) {
      float ov = __shfl_xor(mv, m);
      int   oi = __shfl_xor(mi, m);
      if (ov > mv || (ov == mv && (unsigned)oi < (unsigned)mi)) { mv = ov; mi = oi; }
    }
    t6_consume(t, mi);
    last = mv;
  }
  if (lane == 0) tau[row] = last;
}

// ---------------- MFMA threshold scan: segmented XCD-local appends ----------------
// Grid (N/16) x NC: block owns 16 rows x (N/NC) candidates -> its own buf/cnt
// segments (no cross-block sharing). LDS counters only. Ballot-aggregated writes.
__global__ __launch_bounds__(256) void k_scan2(
    const short* __restrict__ hnb, const float* __restrict__ tau,
    int* __restrict__ cnt, unsigned short* __restrict__ buf, int N) {
  __shared__ int cntl[16];
  int rb = blockIdx.x / NC;          // row group
  int jc = blockIdx.x % NC;          // candidate chunk
  int wave = threadIdx.x >> 6, lane = threadIdx.x & 63;
  int r0 = rb * 16;
  int half = lane >> 4;              // 0..3
  int l16  = lane & 15;

  if (threadIdx.x < 16) cntl[threadIdx.x] = 0;
  __syncthreads();

  bf16x8 a = *(const bf16x8*)(hnb + (size_t)(r0 + l16)*32 + half*8);
  float4 t4 = *(const float4*)(tau + r0 + half*4);
  float tm0 = t4.x - MARGIN, tm1 = t4.y - MARGIN,
        tm2 = t4.z - MARGIN, tm3 = t4.w - MARGIN;
  f32x4 zero = {0.f, 0.f, 0.f, 0.f};

  const int SPANW = N / NC / 4;      // cands per wave (256)
  int jb0 = jc * (N / NC) + wave * SPANW;

#define APPB(R, COND)                                                        \
  {                                                                          \
    unsigned long long mr = __ballot(COND);                                  \
    if (l16 == 0) {                                                          \
      unsigned mask = (unsigned)(mr >> (16*half)) & 0xFFFFu;                 \
      if (mask) {                                                            \
        int row = r0 + half*4 + (R);                                         \
        int pos = atomicAdd(&cntl[4*half + (R)], __popc(mask));              \
        unsigned mm = mask;                                                  \
        while (mm) {                                                         \
          int bx = __ffs(mm) - 1; mm &= mm - 1;                              \
          if (pos < CAPC)                                                    \
            buf[((size_t)row*NC + jc)*CAPC + pos] = (unsigned short)(jb + bx); \
          ++pos;                                                             \
        }                                                                    \
      }                                                                      \
    }                                                                        \
  }

#pragma unroll 4
  for (int jt = 0; jt < SPANW; jt += 16) {
    int jb = jb0 + jt;
    bf16x8 b = *(const bf16x8*)(hnb + (size_t)(jb + l16)*32 + half*8);
    f32x4 d = __builtin_amdgcn_mfma_f32_16x16x32_bf16(a, b, zero, 0, 0, 0);
    bool h0 = d[0] >= tm0, h1 = d[1] >= tm1, h2 = d[2] >= tm2, h3 = d[3] >= tm3;
    if (__any(h0 | h1 | h2 | h3)) {
      APPB(0, h0) APPB(1, h1) APPB(2, h2) APPB(3, h3)
    }
  }
#undef APPB

  __syncthreads();
  if (threadIdx.x < 16)
    cnt[(size_t)(r0 + threadIdx.x)*NC + jc] = min(cntl[threadIdx.x], CAPC);
}

// ---------------- exact top-6 from segmented candidates, wave per row ----
__global__ __launch_bounds__(256) void k_final(
    const float* __restrict__ hn, const unsigned short* __restrict__ buf,
    const int* __restrict__ cnt,
    float* __restrict__ evals, int* __restrict__ eidx,
    float* __restrict__ ownsum, float* insum, int* indeg, int N) {
  int wave = threadIdx.x >> 6, lane = threadIdx.x & 63;
  int row = blockIdx.x * 4 + wave;
  const float4* hn4 = (const float4*)hn;
  float4 q[4];
#pragma unroll
  for (int m = 0; m < 4; ++m) q[m] = hn4[(size_t)row*4 + m];
  Top6 t; t6_init(t);
#pragma unroll
  for (int jc = 0; jc < NC; ++jc) {
    int nseg = cnt[(size_t)row*NC + jc];
    const unsigned short* seg = buf + ((size_t)row*NC + jc)*CAPC;
    for (int e = lane; e < nseg; e += 64) {
      int j = seg[e];
      if (j != row) {
        float4 cv[4];
#pragma unroll
        for (int m = 0; m < 4; ++m) cv[m] = hn4[(size_t)j*4 + m];
        float s = dot16_seq(q, cv);
        t6_insert(t, s, j);
      }
    }
  }
  float osum = 0.f;
  for (int sel = 0; sel < K; ++sel) {
    float cv; int ci;
    t6_best(t, cv, ci);
    float mv = cv; int mi = ci;
#pragma unroll
    for (int m = 1; m < 64; m <<= 1) {
      float ov = __shfl_xor(mv, m);
      int   oi = __shfl_xor(mi, m);
      if (ov > mv || (ov == mv && (unsigned)oi < (unsigned)mi)) { mv = ov; mi = oi; }
    }
    t6_consume(t, mi);
    if (lane == 0) {
      evals[row*K + sel] = mv;
      eidx [row*K + sel] = mi;
      osum += mv;
      atomicAdd(&insum[mi], mv);
      atomicAdd(&indeg[mi], 1);
    }
  }
  if (lane == 0) ownsum[row] = osum;
}

// ------- fused: degree scalars + exclusive scan of (K + indeg) -> CSR offsets ----
__global__ __launch_bounds__(1024) void k_scan(
    const int* __restrict__ indeg, const float* __restrict__ ownsum,
    const float* __restrict__ insum,
    float* __restrict__ rnorm, float* __restrict__ dinv, float* __restrict__ selfc,
    int* __restrict__ cursor, int* __restrict__ offsets, int N) {
  __shared__ int sums[1024];
  int tid = threadIdx.x;
  int per = N >> 10;           // assumes N multiple of 1024
  int base = tid * per;
  int loc[16];
  int s = 0;
  for (int k = 0; k < per; ++k) {
    int i = base + k;
    float rs = 0.5f * (ownsum[i] + insum[i]);
    float rn = 1.f / (rs + 1e-8f);
    float ds = 1.f + rs * rn;
    float di = rsqrtf(fmaxf(ds, 1e-12f));
    rnorm[i] = rn; dinv[i] = di; selfc[i] = di * di; cursor[i] = 0;
    loc[k] = s; s += K + indeg[i];
  }
  sums[tid] = s;
  __syncthreads();
  for (int d = 1; d < 1024; d <<= 1) {
    int v = (tid >= d) ? sums[tid - d] : 0;
    __syncthreads();
    sums[tid] += v;
    __syncthreads();
  }
  int excl = (tid == 0) ? 0 : sums[tid - 1];
  for (int k = 0; k < per; ++k) offsets[base + k] = excl + loc[k];
  if (tid == 1023) offsets[N] = sums[1023];
}

// ---------------- fill symmetrized CSR with fused coefficients ----------------
__global__ void k_fill(const float* __restrict__ evals, const int* __restrict__ eidx,
                       const float* __restrict__ rnorm, const float* __restrict__ dinv,
                       const int* __restrict__ offsets, int* cursor,
                       int* __restrict__ col, float* __restrict__ coef, int N) {
  int e = blockIdx.x * blockDim.x + threadIdx.x;
  if (e >= N * K) return;
  int i = e / K;
  int j = eidx[e];
  float v = evals[e];
  float base = 0.5f * v * dinv[i] * dinv[j];
  int p = atomicAdd(&cursor[i], 1);
  col [offsets[i] + p] = j;
  coef[offsets[i] + p] = base * rnorm[i];
  int q = atomicAdd(&cursor[j], 1);
  col [offsets[j] + q] = i;
  coef[offsets[j] + q] = base * rnorm[j];
}

// ---- DOUT=32 layer: GCN + LN + ReLU + MLP residual, 2 rows/wave,
// ---- epilogue computes next layer's XW row-locally (h shared via LDS).
template<int DIN, int NEXTD>
__global__ __launch_bounds__(256) void k_gpost32(
    const float* __restrict__ XWsrc, const int* __restrict__ offsets,
    const int* __restrict__ col, const float* __restrict__ coef,
    const float* __restrict__ selfc,
    const float* __restrict__ gb, const float* __restrict__ lg, const float* __restrict__ lb,
    const float* __restrict__ hprev,
    const float* __restrict__ w0, const float* __restrict__ b0,
    const float* __restrict__ w1, const float* __restrict__ b1,
    const float* __restrict__ Wnext, float* __restrict__ XWnext,
    float* __restrict__ outp, int N) {
  __shared__ float hid[4][2][32];
  int tid = threadIdx.x;
  int lane = tid & 63, wslot = tid >> 6;
  int sub = lane >> 5, ol = lane & 31;
  int row = (blockIdx.x * 4 + wslot) * 2 + sub;

  float sc = selfc[row];
  float acc0 = sc * XWsrc[(size_t)row*32 + ol];
  int pe = offsets[row + 1];
  for (int q = offsets[row]; q < pe; ++q) {
    int jj = col[q]; float cf = coef[q];
    acc0 = fmaf(cf, XWsrc[(size_t)jj*32 + ol], acc0);
  }
  float u0 = acc0 + gb[ol];
  float s = u0;
#pragma unroll
  for (int m = 1; m < 32; m <<= 1) s += __shfl_xor(s, m);
  float mean = s * (1.f/32.f);
  float d0 = u0 - mean;
  float vs = d0*d0;
#pragma unroll
  for (int m = 1; m < 32; m <<= 1) vs += __shfl_xor(vs, m);
  float rstd = rsqrtf(vs * (1.f/32.f) + 1e-5f);
  float t0 = fmaxf(d0*rstd*lg[ol] + lb[ol], 0.f);

  // MLP residual (hidden via per-wave LDS; same-wave lockstep -> no barrier)
  float hp[DIN];
#pragma unroll
  for (int d = 0; d < DIN; ++d) hp[d] = hprev[(size_t)row*DIN + d];
  float a = b0[ol];
#pragma unroll
  for (int d = 0; d < DIN; ++d) a = fmaf(hp[d], w0[d*32 + ol], a);
  hid[wslot][sub][ol] = fmaxf(a, 0.f);
  float o = b1[ol];
#pragma unroll
  for (int h = 0; h < 32; ++h) o = fmaf(hid[wslot][sub][h], w1[h*32 + ol], o);
  float hv = t0 + o;
  outp[(size_t)row*32 + ol] = hv;

  // epilogue: XWnext = h @ Wnext (h row shared via LDS)
  hid[wslot][sub][ol] = hv;
#pragma unroll
  for (int k2 = 0; k2 < NEXTD/32; ++k2) {
    int oc = ol + 32*k2;
    float acc = 0.f;
#pragma unroll
    for (int d = 0; d < 32; ++d)
      acc = fmaf(hid[wslot][sub][d], Wnext[d*NEXTD + oc], acc);
    XWnext[(size_t)row*NEXTD + oc] = acc;
  }
}

// ---------------- final layer (DOUT=128): gather + LN + relu + MLP residual ----
__global__ __launch_bounds__(256) void k_gpost128(
    const float* __restrict__ XW, const int* __restrict__ offsets,
    const int* __restrict__ col, const float* __restrict__ coef,
    const float* __restrict__ selfc,
    const float* __restrict__ b, const float* __restrict__ g, const float* __restrict__ bt,
    const float* __restrict__ hprev,
    const float* __restrict__ w0, const float* __restrict__ b0,
    const float* __restrict__ w1, const float* __restrict__ b1,
    float* __restrict__ out, int N) {
  __shared__ float hid_s[4][128];
  int wslot = threadIdx.x >> 6;
  int row   = (blockIdx.x * blockDim.x + threadIdx.x) >> 6;
  int lane  = threadIdx.x & 63;
  int o0 = lane, o1 = lane + 64;

  float sc = selfc[row];
  float acc0 = sc * XW[(size_t)row*128 + o0];
  float acc1 = sc * XW[(size_t)row*128 + o1];
  int pe = offsets[row + 1];
  for (int p = offsets[row]; p < pe; ++p) {
    int jj = col[p]; float cf = coef[p];
    acc0 = fmaf(cf, XW[(size_t)jj*128 + o0], acc0);
    acc1 = fmaf(cf, XW[(size_t)jj*128 + o1], acc1);
  }
  float u0 = acc0 + b[o0];
  float u1 = acc1 + b[o1];

  float s = u0 + u1;
#pragma unroll
  for (int m = 1; m < 64; m <<= 1) s += __shfl_xor(s, m);
  float mean = s * (1.f/128.f);
  float d0 = u0 - mean, d1 = u1 - mean;
  float vs = d0*d0 + d1*d1;
#pragma unroll
  for (int m = 1; m < 64; m <<= 1) vs += __shfl_xor(vs, m);
  float rstd = rsqrtf(vs * (1.f/128.f) + 1e-5f);
  float t0 = fmaxf(d0*rstd*g[o0] + bt[o0], 0.f);
  float t1 = fmaxf(d1*rstd*g[o1] + bt[o1], 0.f);

  float hp[32];
#pragma unroll
  for (int d = 0; d < 32; ++d) hp[d] = hprev[(size_t)row*32 + d];
  {
    float a = b0[o0];
#pragma unroll
    for (int d = 0; d < 32; ++d) a = fmaf(hp[d], w0[d*128 + o0], a);
    hid_s[wslot][o0] = fmaxf(a, 0.f);
    float a1 = b0[o1];
#pragma unroll
    for (int d = 0; d < 32; ++d) a1 = fmaf(hp[d], w0[d*128 + o1], a1);
    hid_s[wslot][o1] = fmaxf(a1, 0.f);
  }
  __syncthreads();
  {
    float a = b1[o0];
    for (int h = 0; h < 128; ++h) a = fmaf(hid_s[wslot][h], w1[h*128 + o0], a);
    out[(size_t)row*128 + o0] = t0 + a;
    float a1 = b1[o1];
    for (int h = 0; h < 128; ++h) a1 = fmaf(hid_s[wslot][h], w1[h*128 + o1], a1);
    out[(size_t)row*128 + o1] = t1 + a1;
  }
}

extern "C" void kernel_launch(void* const* d_in, const int* in_sizes, int n_in,
                              void* d_out, int out_size, void* d_ws, size_t ws_size,
                              hipStream_t stream) {
  const float* x    = (const float*)d_in[0];
  const float* Wp   = (const float*)d_in[1];
  const float* bp   = (const float*)d_in[2];
  const float* gw0  = (const float*)d_in[3];
  const float* gb0  = (const float*)d_in[4];
  const float* gw1  = (const float*)d_in[5];
  const float* gb1  = (const float*)d_in[6];
  const float* gw2  = (const float*)d_in[7];
  const float* gb2  = (const float*)d_in[8];
  const float* lg0  = (const float*)d_in[9];
  const float* lb0  = (const float*)d_in[10];
  const float* lg1  = (const float*)d_in[11];
  const float* lb1  = (const float*)d_in[12];
  const float* lg2  = (const float*)d_in[13];
  const float* lb2  = (const float*)d_in[14];
  const float* riw0 = (const float*)d_in[15];
  const float* rib0 = (const float*)d_in[16];
  const float* riw1 = (const float*)d_in[17];
  const float* rib1 = (const float*)d_in[18];
  const float* rhw0 = (const float*)d_in[19];
  const float* rhb0 = (const float*)d_in[20];
  const float* rhw1 = (const float*)d_in[21];
  const float* rhb1 = (const float*)d_in[22];
  const float* row0 = (const float*)d_in[23];
  const float* rob0 = (const float*)d_in[24];
  const float* row1 = (const float*)d_in[25];
  const float* rob1 = (const float*)d_in[26];
  int N = in_sizes[0] / D_IN;   // 8192
  float* out = (float*)d_out;

  char* ws = (char*)d_ws;
  size_t off = 0;
  auto alloc = [&](size_t bytes) -> void* {
    void* p = ws + off;
    off += (bytes + 255) & ~(size_t)255;
    return p;
  };
  float* hn      = (float*)alloc((size_t)N * HP * 4);
  float* evals   = (float*)alloc((size_t)N * K * 4);
  int*   eidx    = (int*)  alloc((size_t)N * K * 4);
  float* ownsum  = (float*)alloc((size_t)N * 4);
  float* insum   = (float*)alloc((size_t)N * 4);
  int*   indeg   = (int*)  alloc((size_t)N * 4);
  float* rnorm   = (float*)alloc((size_t)N * 4);
  float* dinv    = (float*)alloc((size_t)N * 4);
  float* selfc   = (float*)alloc((size_t)N * 4);
  int*   offsets = (int*)  alloc((size_t)(N + 1) * 4);
  int*   cursor  = (int*)  alloc((size_t)N * 4);
  int*   colA    = (int*)  alloc((size_t)N * K * 2 * 4);
  float* coefA   = (float*)alloc((size_t)N * K * 2 * 4);
  float* XWa     = (float*)alloc((size_t)N * 128 * 4);
  float* XWb     = (float*)alloc((size_t)N * 32 * 4);
  float* h1      = (float*)alloc((size_t)N * 32 * 4);
  float* h2      = (float*)alloc((size_t)N * 32 * 4);
  float* tau     = (float*)alloc((size_t)N * 4);
  int*   cnt     = (int*)  alloc((size_t)N * NC * 4);
  unsigned short* buf = (unsigned short*)alloc((size_t)N * NC * CAPC * 2);
  short* hnb     = (short*)alloc((size_t)N * 32 * 2);
  (void)ws_size; (void)n_in; (void)out_size;

  const int B = 256;
  hipLaunchKernelGGL(k_proj, dim3((N + B - 1) / B), dim3(B), 0, stream,
                     x, Wp, bp, gw0, hn, hnb, XWa, insum, indeg, N);
  hipLaunchKernelGGL(k_thresh, dim3(N / 4), dim3(B), 0, stream, hn, tau, N);
  // (N/16) row groups x NC chunks; block owns private buf/cnt segments
  hipLaunchKernelGGL(k_scan2, dim3((N / 16) * NC), dim3(B), 0, stream, hnb, tau, cnt, buf, N);
  hipLaunchKernelGGL(k_final, dim3(N / 4), dim3(B), 0, stream,
                     hn, buf, cnt, evals, eidx, ownsum, insum, indeg, N);
  hipLaunchKernelGGL(k_scan, dim3(1), dim3(1024), 0, stream,
                     indeg, ownsum, insum, rnorm, dinv, selfc, cursor, offsets, N);
  hipLaunchKernelGGL(k_fill, dim3((N * K + B - 1) / B), dim3(B), 0, stream,
                     evals, eidx, rnorm, dinv, offsets, cursor, colA, coefA, N);

  // layer 0: XWa(stride32) -> h1, epilogue XWb = h1 @ gw1
  hipLaunchKernelGGL((k_gpost32<20, 32>), dim3(N / 8), dim3(B), 0, stream,
                     XWa, offsets, colA, coefA, selfc, gb0, lg0, lb0,
                     x, riw0, rib0, riw1, rib1, gw1, XWb, h1, N);
  // layer 1: XWb(stride32) -> h2, epilogue XWa = h2 @ gw2 (stride128)
  hipLaunchKernelGGL((k_gpost32<32, 128>), dim3(N / 8), dim3(B), 0, stream,
                     XWb, offsets, colA, coefA, selfc, gb1, lg1, lb1,
                     h1, rhw0, rhb0, rhw1, rhb1, gw2, XWa, h2, N);
  // layer 2: XWa(stride128) -> out
  hipLaunchKernelGGL(k_gpost128, dim3(N / 4), dim3(B), 0, stream,
                     XWa, offsets, colA, coefA, selfc, gb2, lg2, lb2,
                     h2, row0, rob0, row1, rob1, out, N);
}

// Round 16
// 164.773 us; speedup vs baseline: 5.6450x; 1.2194x over previous
//
#include <hip/hip_runtime.h>

constexpr int D_IN = 20;   // input feature dim
constexpr int HP   = 16;   // projection dim
constexpr int K    = 6;    // neighbors
constexpr int SAMP = 512;  // threshold sample size
constexpr int NC   = 8;    // candidate chunks (segmented buffers)
constexpr int CAPC = 192;  // per-(row,chunk) buffer capacity
constexpr int CIN  = 128;  // per-row in-edge slots (indeg ~Poisson(6); 128 = ~20x mean)
constexpr float MARGIN = 0.02f;  // covers bf16-vs-fp32 dot error

typedef __attribute__((ext_vector_type(8))) short bf16x8;
typedef __attribute__((ext_vector_type(4))) float f32x4;

// Sequential fmaf dot — MUST be bit-identical across thresh/final.
__device__ __forceinline__ float dot16_seq(const float4* q, const float4* c) {
  float s = 0.f;
#pragma unroll
  for (int m = 0; m < 4; ++m) {
    s = fmaf(q[m].x, c[m].x, s);
    s = fmaf(q[m].y, c[m].y, s);
    s = fmaf(q[m].z, c[m].z, s);
    s = fmaf(q[m].w, c[m].w, s);
  }
  return s;
}

// round-to-nearest-even f32 -> bf16 bits
__device__ __forceinline__ short f2bf(float f) {
  unsigned u = __float_as_uint(f);
  unsigned r = (u + 0x7fffu + ((u >> 16) & 1u)) >> 16;
  return (short)r;
}

// inline degree scalars (identical fp32 ops as the old k_deg -> same bits)
__device__ __forceinline__ float dinv_of(float own, float ins) {
  float rs = 0.5f * (own + ins);
  float rn = 1.f / (rs + 1e-8f);
  return rsqrtf(fmaxf(1.f + rs * rn, 1e-12f));
}

// ---- projection + row-normalize + bf16 copy + XW0 + counter zeroing ----
__global__ void k_proj(const float* __restrict__ x, const float* __restrict__ Wp,
                       const float* __restrict__ bp, const float* __restrict__ gw0,
                       float* __restrict__ hn, short* __restrict__ hnb,
                       float* __restrict__ XW0,
                       float* __restrict__ insum, int* __restrict__ indeg, int N) {
  int i = blockIdx.x * blockDim.x + threadIdx.x;
  if (i >= N) return;
  insum[i] = 0.f; indeg[i] = 0;
  float xr[D_IN];
#pragma unroll
  for (int d = 0; d < D_IN; ++d) xr[d] = x[i*D_IN + d];
  float hv[HP];
  float nrm2 = 0.f;
#pragma unroll
  for (int h = 0; h < HP; ++h) {
    float a = bp[h];
#pragma unroll
    for (int d = 0; d < D_IN; ++d) a += xr[d] * Wp[d*HP + h];
    hv[h] = a;
    nrm2 += a * a;
  }
  float inv = 1.f / fmaxf(sqrtf(nrm2), 1e-12f);
#pragma unroll
  for (int h = 0; h < HP; ++h) {
    float v = hv[h] * inv;
    hn[i*HP + h] = v;
    hnb[(size_t)i*32 + h] = f2bf(v);
  }
#pragma unroll
  for (int h = 0; h < HP; ++h) hnb[(size_t)i*32 + 16 + h] = 0;
  // fused XW0 = x @ gw0 (bias added in gpost)
#pragma unroll
  for (int oc = 0; oc < 32; ++oc) {
    float a = 0.f;
#pragma unroll
    for (int d = 0; d < D_IN; ++d) a += xr[d] * gw0[d*32 + oc];
    XW0[(size_t)i*32 + oc] = a;
  }
}

// ---------------- per-lane top-6 in NAMED registers ----
struct Top6 { float v0,v1,v2,v3,v4,v5; int i0,i1,i2,i3,i4,i5; };

__device__ __forceinline__ void t6_init(Top6& t) {
  t.v0=t.v1=t.v2=t.v3=t.v4=t.v5=-1e30f;
  t.i0=t.i1=t.i2=t.i3=t.i4=t.i5=-1;
}

#define T6_SWAP(a,b,ia,ib) { float tv=a; a=b; b=tv; int ti=ia; ia=ib; ib=ti; }

__device__ __forceinline__ void t6_insert(Top6& t, float s, int c) {
  if (s > t.v5) {
    t.v5 = s; t.i5 = c;
    if (t.v5 > t.v4) { T6_SWAP(t.v4, t.v5, t.i4, t.i5); }
    if (t.v4 > t.v3) { T6_SWAP(t.v3, t.v4, t.i3, t.i4); }
    if (t.v3 > t.v2) { T6_SWAP(t.v2, t.v3, t.i2, t.i3); }
    if (t.v2 > t.v1) { T6_SWAP(t.v1, t.v2, t.i1, t.i2); }
    if (t.v1 > t.v0) { T6_SWAP(t.v0, t.v1, t.i0, t.i1); }
  }
}

__device__ __forceinline__ void t6_best(const Top6& t, float& cv, int& ci) {
  cv = t.v0; ci = t.i0;
  if (t.v1 > cv || (t.v1 == cv && (unsigned)t.i1 < (unsigned)ci)) { cv = t.v1; ci = t.i1; }
  if (t.v2 > cv || (t.v2 == cv && (unsigned)t.i2 < (unsigned)ci)) { cv = t.v2; ci = t.i2; }
  if (t.v3 > cv || (t.v3 == cv && (unsigned)t.i3 < (unsigned)ci)) { cv = t.v3; ci = t.i3; }
  if (t.v4 > cv || (t.v4 == cv && (unsigned)t.i4 < (unsigned)ci)) { cv = t.v4; ci = t.i4; }
  if (t.v5 > cv || (t.v5 == cv && (unsigned)t.i5 < (unsigned)ci)) { cv = t.v5; ci = t.i5; }
}

__device__ __forceinline__ void t6_consume(Top6& t, int mi) {
  if (t.i0 == mi) t.v0 = -1e30f;
  if (t.i1 == mi) t.v1 = -1e30f;
  if (t.i2 == mi) t.v2 = -1e30f;
  if (t.i3 == mi) t.v3 = -1e30f;
  if (t.i4 == mi) t.v4 = -1e30f;
  if (t.i5 == mi) t.v5 = -1e30f;
}

// ---------------- threshold pass: exact 6th-largest over SAMP-sample, wave per row
__global__ __launch_bounds__(256) void k_thresh(const float* __restrict__ hn,
                                                float* __restrict__ tau, int N) {
  int wave = threadIdx.x >> 6, lane = threadIdx.x & 63;
  int row = blockIdx.x * 4 + wave;
  const float4* hn4 = (const float4*)hn;
  float4 q[4];
#pragma unroll
  for (int m = 0; m < 4; ++m) q[m] = hn4[(size_t)row*4 + m];
  Top6 t; t6_init(t);
#pragma unroll
  for (int k = 0; k < SAMP/64; ++k) {
    int c = lane + 64*k;
    if (c != row) {
      float4 cv[4];
#pragma unroll
      for (int m = 0; m < 4; ++m) cv[m] = hn4[(size_t)c*4 + m];
      float s = dot16_seq(q, cv);
      t6_insert(t, s, c);
    }
  }
  float last = -1e30f;
  for (int sel = 0; sel < K; ++sel) {
    float cv; int ci;
    t6_best(t, cv, ci);
    float mv = cv; int mi = ci;
#pragma unroll
    for (int m = 1; m < 64; m <<= 1) {
      float ov = __shfl_xor(mv, m);
      int   oi = __shfl_xor(mi, m);
      if (ov > mv || (ov == mv && (unsigned)oi < (unsigned)mi)) { mv = ov; mi = oi; }
    }
    t6_consume(t, mi);
    last = mv;
  }
  if (lane == 0) tau[row] = last;
}

// ---------------- MFMA threshold scan: segmented XCD-local appends ----------------
__global__ __launch_bounds__(256) void k_scan2(
    const short* __restrict__ hnb, const float* __restrict__ tau,
    int* __restrict__ cnt, unsigned short* __restrict__ buf, int N) {
  __shared__ int cntl[16];
  int rb = blockIdx.x / NC;          // row group
  int jc = blockIdx.x % NC;          // candidate chunk
  int wave = threadIdx.x >> 6, lane = threadIdx.x & 63;
  int r0 = rb * 16;
  int half = lane >> 4;              // 0..3
  int l16  = lane & 15;

  if (threadIdx.x < 16) cntl[threadIdx.x] = 0;
  __syncthreads();

  bf16x8 a = *(const bf16x8*)(hnb + (size_t)(r0 + l16)*32 + half*8);
  float4 t4 = *(const float4*)(tau + r0 + half*4);
  float tm0 = t4.x - MARGIN, tm1 = t4.y - MARGIN,
        tm2 = t4.z - MARGIN, tm3 = t4.w - MARGIN;
  f32x4 zero = {0.f, 0.f, 0.f, 0.f};

  const int SPANW = N / NC / 4;      // cands per wave (256)
  int jb0 = jc * (N / NC) + wave * SPANW;

#define APPB(R, COND)                                                        \
  {                                                                          \
    unsigned long long mr = __ballot(COND);                                  \
    if (l16 == 0) {                                                          \
      unsigned mask = (unsigned)(mr >> (16*half)) & 0xFFFFu;                 \
      if (mask) {                                                            \
        int row = r0 + half*4 + (R);                                         \
        int pos = atomicAdd(&cntl[4*half + (R)], __popc(mask));              \
        unsigned mm = mask;                                                  \
        while (mm) {                                                         \
          int bx = __ffs(mm) - 1; mm &= mm - 1;                              \
          if (pos < CAPC)                                                    \
            buf[((size_t)row*NC + jc)*CAPC + pos] = (unsigned short)(jb + bx); \
          ++pos;                                                             \
        }                                                                    \
      }                                                                      \
    }                                                                        \
  }

#pragma unroll 4
  for (int jt = 0; jt < SPANW; jt += 16) {
    int jb = jb0 + jt;
    bf16x8 b = *(const bf16x8*)(hnb + (size_t)(jb + l16)*32 + half*8);
    f32x4 d = __builtin_amdgcn_mfma_f32_16x16x32_bf16(a, b, zero, 0, 0, 0);
    bool h0 = d[0] >= tm0, h1 = d[1] >= tm1, h2 = d[2] >= tm2, h3 = d[3] >= tm3;
    if (__any(h0 | h1 | h2 | h3)) {
      APPB(0, h0) APPB(1, h1) APPB(2, h2) APPB(3, h3)
    }
  }
#undef APPB

  __syncthreads();
  if (threadIdx.x < 16)
    cnt[(size_t)(r0 + threadIdx.x)*NC + jc] = min(cntl[threadIdx.x], CAPC);
}

// ---- exact top-6 (flattened segments) + direct in-edge slot writes, wave per row --
__global__ __launch_bounds__(256) void k_final(
    const float* __restrict__ hn, const unsigned short* __restrict__ buf,
    const int* __restrict__ cnt,
    float* __restrict__ evals, int* __restrict__ eidx,
    float* __restrict__ ownsum, float* insum, int* indeg,
    unsigned short* __restrict__ incol, float* __restrict__ inval, int N) {
  int wave = threadIdx.x >> 6, lane = threadIdx.x & 63;
  int row = blockIdx.x * 4 + wave;
  const float4* hn4 = (const float4*)hn;
  float4 q[4];
#pragma unroll
  for (int m = 0; m < 4; ++m) q[m] = hn4[(size_t)row*4 + m];

  // flatten the 8 segments: lanes share all candidates instead of 8 serial loops
  int cbase = row * NC;
  int cl = (lane < NC) ? cnt[cbase + lane] : 0;
  int c0 = __shfl(cl, 0), c1 = __shfl(cl, 1), c2 = __shfl(cl, 2), c3 = __shfl(cl, 3),
      c4 = __shfl(cl, 4), c5 = __shfl(cl, 5), c6 = __shfl(cl, 6), c7 = __shfl(cl, 7);
  int p1 = c0, p2 = p1 + c1, p3 = p2 + c2, p4 = p3 + c3,
      p5 = p4 + c4, p6 = p5 + c5, p7 = p6 + c6, T = p7 + c7;

  Top6 t; t6_init(t);
  for (int e = lane; e < T; e += 64) {
    int s, off;
    if (e < p4) {
      if (e < p2) { if (e < p1) { s = 0; off = e; } else { s = 1; off = e - p1; } }
      else        { if (e < p3) { s = 2; off = e - p2; } else { s = 3; off = e - p3; } }
    } else {
      if (e < p6) { if (e < p5) { s = 4; off = e - p4; } else { s = 5; off = e - p5; } }
      else        { if (e < p7) { s = 6; off = e - p6; } else { s = 7; off = e - p7; } }
    }
    int j = buf[((size_t)cbase + s)*CAPC + off];
    if (j != row) {
      float4 cv[4];
#pragma unroll
      for (int m = 0; m < 4; ++m) cv[m] = hn4[(size_t)j*4 + m];
      float sc = dot16_seq(q, cv);
      t6_insert(t, sc, j);
    }
  }
  float osum = 0.f;
  for (int sel = 0; sel < K; ++sel) {
    float cv; int ci;
    t6_best(t, cv, ci);
    float mv = cv; int mi = ci;
#pragma unroll
    for (int m = 1; m < 64; m <<= 1) {
      float ov = __shfl_xor(mv, m);
      int   oi = __shfl_xor(mi, m);
      if (ov > mv || (ov == mv && (unsigned)oi < (unsigned)mi)) { mv = ov; mi = oi; }
    }
    t6_consume(t, mi);
    if (lane == 0) {
      evals[row*K + sel] = mv;
      eidx [row*K + sel] = mi;
      osum += mv;
      atomicAdd(&insum[mi], mv);
      int pos = atomicAdd(&indeg[mi], 1);
      if (pos < CIN) {
        incol[(size_t)mi*CIN + pos] = (unsigned short)row;
        inval[(size_t)mi*CIN + pos] = mv;
      }
    }
  }
  if (lane == 0) ownsum[row] = osum;
}

// ---- DOUT=32 layer: GCN (inline coef) + LN + ReLU + MLP residual, 2 rows/wave,
// ---- epilogue computes next layer's XW row-locally (h shared via LDS).
template<int DIN, int NEXTD>
__global__ __launch_bounds__(256) void k_gpost32(
    const float* __restrict__ XWsrc,
    const int* __restrict__ eidx, const float* __restrict__ evals,
    const unsigned short* __restrict__ incol, const float* __restrict__ inval,
    const int* __restrict__ indeg,
    const float* __restrict__ ownsum, const float* __restrict__ insum,
    const float* __restrict__ gb, const float* __restrict__ lg, const float* __restrict__ lb,
    const float* __restrict__ hprev,
    const float* __restrict__ w0, const float* __restrict__ b0,
    const float* __restrict__ w1, const float* __restrict__ b1,
    const float* __restrict__ Wnext, float* __restrict__ XWnext,
    float* __restrict__ outp, int N) {
  __shared__ float hid[4][2][32];
  int tid = threadIdx.x;
  int lane = tid & 63, wslot = tid >> 6;
  int sub = lane >> 5, ol = lane & 31;
  int row = (blockIdx.x * 4 + wslot) * 2 + sub;

  float rs_i = 0.5f * (ownsum[row] + insum[row]);
  float rn_i = 1.f / (rs_i + 1e-8f);
  float di_i = rsqrtf(fmaxf(1.f + rs_i * rn_i, 1e-12f));
  float cc = 0.5f * di_i * rn_i;
  float acc = (di_i * di_i) * XWsrc[(size_t)row*32 + ol];
#pragma unroll
  for (int t = 0; t < K; ++t) {
    int j = eidx[row*K + t]; float v = evals[row*K + t];
    float dj = dinv_of(ownsum[j], insum[j]);
    acc = fmaf(cc * v * dj, XWsrc[(size_t)j*32 + ol], acc);
  }
  int ne = min(indeg[row], CIN);
  for (int e = 0; e < ne; ++e) {
    int j = incol[(size_t)row*CIN + e]; float v = inval[(size_t)row*CIN + e];
    float dj = dinv_of(ownsum[j], insum[j]);
    acc = fmaf(cc * v * dj, XWsrc[(size_t)j*32 + ol], acc);
  }
  float u0 = acc + gb[ol];
  float s = u0;
#pragma unroll
  for (int m = 1; m < 32; m <<= 1) s += __shfl_xor(s, m);
  float mean = s * (1.f/32.f);
  float d0 = u0 - mean;
  float vs = d0*d0;
#pragma unroll
  for (int m = 1; m < 32; m <<= 1) vs += __shfl_xor(vs, m);
  float rstd = rsqrtf(vs * (1.f/32.f) + 1e-5f);
  float t0 = fmaxf(d0*rstd*lg[ol] + lb[ol], 0.f);

  // MLP residual (per-wave LDS; same-wave lockstep -> no barrier)
  float hp[DIN];
#pragma unroll
  for (int d = 0; d < DIN; ++d) hp[d] = hprev[(size_t)row*DIN + d];
  float a = b0[ol];
#pragma unroll
  for (int d = 0; d < DIN; ++d) a = fmaf(hp[d], w0[d*32 + ol], a);
  hid[wslot][sub][ol] = fmaxf(a, 0.f);
  float o = b1[ol];
#pragma unroll
  for (int h = 0; h < 32; ++h) o = fmaf(hid[wslot][sub][h], w1[h*32 + ol], o);
  float hv = t0 + o;
  outp[(size_t)row*32 + ol] = hv;

  // epilogue: XWnext = h @ Wnext (h row shared via LDS)
  hid[wslot][sub][ol] = hv;
#pragma unroll
  for (int k2 = 0; k2 < NEXTD/32; ++k2) {
    int oc = ol + 32*k2;
    float acc2 = 0.f;
#pragma unroll
    for (int d = 0; d < 32; ++d)
      acc2 = fmaf(hid[wslot][sub][d], Wnext[d*NEXTD + oc], acc2);
    XWnext[(size_t)row*NEXTD + oc] = acc2;
  }
}

// ---------------- final layer (DOUT=128): inline-coef gather + LN + relu + MLP ----
__global__ __launch_bounds__(256) void k_gpost128(
    const float* __restrict__ XW,
    const int* __restrict__ eidx, const float* __restrict__ evals,
    const unsigned short* __restrict__ incol, const float* __restrict__ inval,
    const int* __restrict__ indeg,
    const float* __restrict__ ownsum, const float* __restrict__ insum,
    const float* __restrict__ b, const float* __restrict__ g, const float* __restrict__ bt,
    const float* __restrict__ hprev,
    const float* __restrict__ w0, const float* __restrict__ b0,
    const float* __restrict__ w1, const float* __restrict__ b1,
    float* __restrict__ out, int N) {
  __shared__ float hid_s[4][128];
  int wslot = threadIdx.x >> 6;
  int row   = (blockIdx.x * blockDim.x + threadIdx.x) >> 6;
  int lane  = threadIdx.x & 63;
  int o0 = lane, o1 = lane + 64;

  float rs_i = 0.5f * (ownsum[row] + insum[row]);
  float rn_i = 1.f / (rs_i + 1e-8f);
  float di_i = rsqrtf(fmaxf(1.f + rs_i * rn_i, 1e-12f));
  float cc = 0.5f * di_i * rn_i;
  float sc = di_i * di_i;
  float acc0 = sc * XW[(size_t)row*128 + o0];
  float acc1 = sc * XW[(size_t)row*128 + o1];
#pragma unroll
  for (int t = 0; t < K; ++t) {
    int j = eidx[row*K + t]; float v = evals[row*K + t];
    float dj = dinv_of(ownsum[j], insum[j]);
    float cf = cc * v * dj;
    acc0 = fmaf(cf, XW[(size_t)j*128 + o0], acc0);
    acc1 = fmaf(cf, XW[(size_t)j*128 + o1], acc1);
  }
  int ne = min(indeg[row], CIN);
  for (int e = 0; e < ne; ++e) {
    int j = incol[(size_t)row*CIN + e]; float v = inval[(size_t)row*CIN + e];
    float dj = dinv_of(ownsum[j], insum[j]);
    float cf = cc * v * dj;
    acc0 = fmaf(cf, XW[(size_t)j*128 + o0], acc0);
    acc1 = fmaf(cf, XW[(size_t)j*128 + o1], acc1);
  }
  float u0 = acc0 + b[o0];
  float u1 = acc1 + b[o1];

  float s = u0 + u1;
#pragma unroll
  for (int m = 1; m < 64; m <<= 1) s += __shfl_xor(s, m);
  float mean = s * (1.f/128.f);
  float d0 = u0 - mean, d1 = u1 - mean;
  float vs = d0*d0 + d1*d1;
#pragma unroll
  for (int m = 1; m < 64; m <<= 1) vs += __shfl_xor(vs, m);
  float rstd = rsqrtf(vs * (1.f/128.f) + 1e-5f);
  float t0 = fmaxf(d0*rstd*g[o0] + bt[o0], 0.f);
  float t1 = fmaxf(d1*rstd*g[o1] + bt[o1], 0.f);

  float hp[32];
#pragma unroll
  for (int d = 0; d < 32; ++d) hp[d] = hprev[(size_t)row*32 + d];
  {
    float a = b0[o0];
#pragma unroll
    for (int d = 0; d < 32; ++d) a = fmaf(hp[d], w0[d*128 + o0], a);
    hid_s[wslot][o0] = fmaxf(a, 0.f);
    float a1 = b0[o1];
#pragma unroll
    for (int d = 0; d < 32; ++d) a1 = fmaf(hp[d], w0[d*128 + o1], a1);
    hid_s[wslot][o1] = fmaxf(a1, 0.f);
  }
  __syncthreads();
  {
    float a = b1[o0];
#pragma unroll 4
    for (int h = 0; h < 128; ++h) a = fmaf(hid_s[wslot][h], w1[h*128 + o0], a);
    out[(size_t)row*128 + o0] = t0 + a;
    float a1 = b1[o1];
#pragma unroll 4
    for (int h = 0; h < 128; ++h) a1 = fmaf(hid_s[wslot][h], w1[h*128 + o1], a1);
    out[(size_t)row*128 + o1] = t1 + a1;
  }
}

extern "C" void kernel_launch(void* const* d_in, const int* in_sizes, int n_in,
                              void* d_out, int out_size, void* d_ws, size_t ws_size,
                              hipStream_t stream) {
  const float* x    = (const float*)d_in[0];
  const float* Wp   = (const float*)d_in[1];
  const float* bp   = (const float*)d_in[2];
  const float* gw0  = (const float*)d_in[3];
  const float* gb0  = (const float*)d_in[4];
  const float* gw1  = (const float*)d_in[5];
  const float* gb1  = (const float*)d_in[6];
  const float* gw2  = (const float*)d_in[7];
  const float* gb2  = (const float*)d_in[8];
  const float* lg0  = (const float*)d_in[9];
  const float* lb0  = (const float*)d_in[10];
  const float* lg1  = (const float*)d_in[11];
  const float* lb1  = (const float*)d_in[12];
  const float* lg2  = (const float*)d_in[13];
  const float* lb2  = (const float*)d_in[14];
  const float* riw0 = (const float*)d_in[15];
  const float* rib0 = (const float*)d_in[16];
  const float* riw1 = (const float*)d_in[17];
  const float* rib1 = (const float*)d_in[18];
  const float* rhw0 = (const float*)d_in[19];
  const float* rhb0 = (const float*)d_in[20];
  const float* rhw1 = (const float*)d_in[21];
  const float* rhb1 = (const float*)d_in[22];
  const float* row0 = (const float*)d_in[23];
  const float* rob0 = (const float*)d_in[24];
  const float* row1 = (const float*)d_in[25];
  const float* rob1 = (const float*)d_in[26];
  int N = in_sizes[0] / D_IN;   // 8192
  float* out = (float*)d_out;

  char* ws = (char*)d_ws;
  size_t off = 0;
  auto alloc = [&](size_t bytes) -> void* {
    void* p = ws + off;
    off += (bytes + 255) & ~(size_t)255;
    return p;
  };
  float* hn      = (float*)alloc((size_t)N * HP * 4);
  float* evals   = (float*)alloc((size_t)N * K * 4);
  int*   eidx    = (int*)  alloc((size_t)N * K * 4);
  float* ownsum  = (float*)alloc((size_t)N * 4);
  float* insum   = (float*)alloc((size_t)N * 4);
  int*   indeg   = (int*)  alloc((size_t)N * 4);
  float* XWa     = (float*)alloc((size_t)N * 128 * 4);
  float* XWb     = (float*)alloc((size_t)N * 32 * 4);
  float* h1      = (float*)alloc((size_t)N * 32 * 4);
  float* h2      = (float*)alloc((size_t)N * 32 * 4);
  float* tau     = (float*)alloc((size_t)N * 4);
  int*   cnt     = (int*)  alloc((size_t)N * NC * 4);
  unsigned short* buf = (unsigned short*)alloc((size_t)N * NC * CAPC * 2);
  short* hnb     = (short*)alloc((size_t)N * 32 * 2);
  unsigned short* incol = (unsigned short*)alloc((size_t)N * CIN * 2);
  float* inval   = (float*)alloc((size_t)N * CIN * 4);
  (void)ws_size; (void)n_in; (void)out_size;

  const int B = 256;
  hipLaunchKernelGGL(k_proj, dim3((N + B - 1) / B), dim3(B), 0, stream,
                     x, Wp, bp, gw0, hn, hnb, XWa, insum, indeg, N);
  hipLaunchKernelGGL(k_thresh, dim3(N / 4), dim3(B), 0, stream, hn, tau, N);
  hipLaunchKernelGGL(k_scan2, dim3((N / 16) * NC), dim3(B), 0, stream, hnb, tau, cnt, buf, N);
  hipLaunchKernelGGL(k_final, dim3(N / 4), dim3(B), 0, stream,
                     hn, buf, cnt, evals, eidx, ownsum, insum, indeg, incol, inval, N);

  // layer 0: XWa(stride32) -> h1, epilogue XWb = h1 @ gw1
  hipLaunchKernelGGL((k_gpost32<20, 32>), dim3(N / 8), dim3(B), 0, stream,
                     XWa, eidx, evals, incol, inval, indeg, ownsum, insum,
                     gb0, lg0, lb0, x, riw0, rib0, riw1, rib1, gw1, XWb, h1, N);
  // layer 1: XWb(stride32) -> h2, epilogue XWa = h2 @ gw2 (stride128)
  hipLaunchKernelGGL((k_gpost32<32, 128>), dim3(N / 8), dim3(B), 0, stream,
                     XWb, eidx, evals, incol, inval, indeg, ownsum, insum,
                     gb1, lg1, lb1, h1, rhw0, rhb0, rhw1, rhb1, gw2, XWa, h2, N);
  // layer 2: XWa(stride128) -> out
  hipLaunchKernelGGL(k_gpost128, dim3(N / 4), dim3(B), 0, stream,
                     XWa, eidx, evals, incol, inval, indeg, ownsum, insum,
                     gb2, lg2, lb2, h2, row0, rob0, row1, rob1, out, N);
}